// Round 17
// baseline (125.028 us; speedup 1.0000x reference)
//
#include <hip/hip_runtime.h>

#define NCHEB 8

typedef __attribute__((ext_vector_type(8))) short vs8;
typedef __attribute__((ext_vector_type(4))) float vf4;
typedef __attribute__((ext_vector_type(16))) float vf16;

__device__ __forceinline__ unsigned short f2bf(float f) {
  union { float f; unsigned int u; } x; x.f = f;
  unsigned int r = (x.u + 0x7FFFu + ((x.u >> 16) & 1u)) >> 16;
  return (unsigned short)r;
}

// DPP move: 0x138 = wave_shr:1 (lane l <- l-1), 0x130 = wave_shl:1 (l <- l+1),
// 0xB1 = quad_perm xor1, 0x4E = quad_perm xor2, 0x128 = row_ror:8 (xor8).
template<int CTRL>
__device__ __forceinline__ float dppf(float x) {
  return __int_as_float(__builtin_amdgcn_mov_dpp(__float_as_int(x), CTRL, 0xF, 0xF, true));
}

// ---------------------------------------------------------------------------
// MFMA 3x3 SAME conv, co-tile split (R13's proven kernel, unchanged).
// ---------------------------------------------------------------------------
template<int COUT, int TILES, bool SE>
__global__ __launch_bounds__(256) void k_conv(
    const float* __restrict__ inA, const float* __restrict__ inB,
    const float* __restrict__ wA, const float* __restrict__ bA,
    const float* __restrict__ wB, const float* __restrict__ bB,
    float* __restrict__ outA, float* __restrict__ outB,
    int actA, int actB,
    const float* __restrict__ x,
    const float* __restrict__ sw1, const float* __restrict__ sb1,
    const float* __restrict__ sw2, const float* __restrict__ sb2,
    float* __restrict__ seo) {
  __shared__ unsigned short Xl[256 * 64];
  __shared__ unsigned short Wl[9 * 16 * 64];
  __shared__ float sp[64];
  __shared__ float sh1[32];
  const int b = blockIdx.x;
  const int t = threadIdx.x;

  if (SE && b >= 8 * TILES) {
    const int n = b - 8 * TILES;
    const int c = t >> 2, part = t & 3;
    const float* xp = x + (n * 64 + c) * 256 + part * 64;
    float s = 0.f;
    for (int k = 0; k < 64; ++k) s += xp[k];
    s += __shfl_xor(s, 1, 64);
    s += __shfl_xor(s, 2, 64);
    if (part == 0) sp[c] = s * (1.f / 256.f);
    __syncthreads();
    if (t < 32) {
      float a = sb1[t];
      for (int k = 0; k < 64; ++k) a += sw1[t * 64 + k] * sp[k];
      sh1[t] = a > 0.f ? a : 0.01f * a;
    }
    __syncthreads();
    if (t < 16) {
      float a = sb2[t];
      for (int k = 0; k < 32; ++k) a += sw2[t * 32 + k] * sh1[k];
      seo[n * 16 + t] = 1.f / (1.f + __expf(-a));
    }
    return;
  }

  const int n = b & 3;
  const int q = b >> 2;
  const int br = (q >= TILES) ? 1 : 0;
  const int ct = q - br * TILES;
  const int co0 = ct * 16;
  const float* inp = (br ? inB : inA) + n * 64 * 256;
  const float* wsrc = br ? wB : wA;
  const float* bias = br ? bB : bA;
  float* outp = (br ? outB : outA) + n * COUT * 256;
  const int act = br ? actB : actA;

  {
    const int p = t;
    #pragma unroll
    for (int q8 = 0; q8 < 8; ++q8) {
      vs8 v;
      #pragma unroll
      for (int j = 0; j < 8; ++j) v[j] = (short)f2bf(inp[(8 * q8 + j) * 256 + p]);
      *(vs8*)&Xl[p * 64 + ((q8 ^ (p & 7)) << 3)] = v;
    }
  }
  {
    const int col = t >> 4;
    const int sub = t & 15;
    const int co = co0 + col;
    if (co < COUT) {
      const float* wp = wsrc + (co * 64 + sub * 4) * 9;
      #pragma unroll
      for (int cc = 0; cc < 4; ++cc) {
        const int ci = sub * 4 + cc;
        #pragma unroll
        for (int e = 0; e < 9; ++e)
          Wl[(e * 16 + col) * 64 + (ci ^ ((col & 7) << 3))] = f2bf(wp[cc * 9 + e]);
      }
    } else {
      #pragma unroll
      for (int cc = 0; cc < 4; ++cc) {
        const int ci = sub * 4 + cc;
        #pragma unroll
        for (int e = 0; e < 9; ++e)
          Wl[(e * 16 + col) * 64 + (ci ^ ((col & 7) << 3))] = 0;
      }
    }
  }
  __syncthreads();

  const int w = t >> 6, lane = t & 63;
  const int px = lane & 15, kg = lane >> 4;
  vf4 acc[4];
  #pragma unroll
  for (int mt = 0; mt < 4; ++mt) acc[mt] = (vf4)0.f;

  for (int e = 0; e < 9; ++e) {
    const int dy = e / 3 - 1, dx = e % 3 - 1;
    const bool xok = (dx == 0) || (dx < 0 ? (px > 0) : (px < 15));
    const int xoff = xok ? dx : 0;
    #pragma unroll
    for (int ks = 0; ks < 2; ++ks) {
      vs8 bf = *(const vs8*)&Wl[(e * 16 + px) * 64 + (((ks * 4 + kg) ^ (px & 7)) << 3)];
      #pragma unroll
      for (int mt = 0; mt < 4; ++mt) {
        const int yy = 4 * w + mt + dy;
        if (yy < 0 || yy > 15) continue;
        const int ps = yy * 16 + px + xoff;
        vs8 a = *(const vs8*)&Xl[ps * 64 + (((ks * 4 + kg) ^ (ps & 7)) << 3)];
        if (!xok) a = (vs8)(short)0;
        acc[mt] = __builtin_amdgcn_mfma_f32_16x16x32_bf16(a, bf, acc[mt], 0, 0, 0);
      }
    }
  }

  const int co = co0 + px;
  if (co < COUT) {
    const float bv = bias[co];
    #pragma unroll
    for (int mt = 0; mt < 4; ++mt) {
      const int y = 4 * w + mt;
      vf4 v = acc[mt];
      #pragma unroll
      for (int j = 0; j < 4; ++j) {
        float s = v[j] + bv;
        if (act == 1) s = s > 0.f ? s : 0.01f * s;
        else if (act == 2) s = 1.f / (1.f + __expf(-s));
        v[j] = s;
      }
      *(vf4*)&outp[co * 256 + y * 16 + kg * 4] = v;
    }
  }
}

// ---------------------------------------------------------------------------
// Fused GroupNorm(1,16) + SE + post conv (R13's proven kernel, unchanged).
// ---------------------------------------------------------------------------
__global__ __launch_bounds__(512) void k_post(
    const float* __restrict__ sol, const float* __restrict__ se,
    const float* __restrict__ gn_w, const float* __restrict__ gn_b,
    const float* __restrict__ pw, const float* __restrict__ pb,
    float* __restrict__ out) {
  __shared__ unsigned short Hl[256 * 24];
  __shared__ unsigned short Wp[9 * 128 * 24];
  __shared__ float rs[8];
  __shared__ float rs2[8];
  const int n = blockIdx.x;
  const int t = threadIdx.x;
  const int w = t >> 6, lane = t & 63;

  float v[8];
  {
    const vf4* s4 = (const vf4*)(sol + n * 4096 + 8 * t);
    vf4 a = s4[0], b = s4[1];
    v[0]=a[0];v[1]=a[1];v[2]=a[2];v[3]=a[3];v[4]=b[0];v[5]=b[1];v[6]=b[2];v[7]=b[3];
  }
  float s = 0.f, s2 = 0.f;
  #pragma unroll
  for (int k = 0; k < 8; ++k) { s += v[k]; s2 += v[k] * v[k]; }
  #pragma unroll
  for (int o = 1; o <= 32; o <<= 1) { s += __shfl_xor(s, o, 64); s2 += __shfl_xor(s2, o, 64); }
  if (lane == 0) { rs[w] = s; rs2[w] = s2; }

  {
    const int co = t >> 2, sub = t & 3;
    const float* wp0 = pw + (co * 16 + sub * 4) * 9;
    #pragma unroll
    for (int cc = 0; cc < 4; ++cc) {
      const int ci = sub * 4 + cc;
      #pragma unroll
      for (int e = 0; e < 9; ++e)
        Wp[(e * 128 + co) * 24 + ci] = f2bf(wp0[cc * 9 + e]);
    }
  }
  __syncthreads();
  float sm = 0.f, sq = 0.f;
  #pragma unroll
  for (int k = 0; k < 8; ++k) { sm += rs[k]; sq += rs2[k]; }
  const float mu = sm * (1.f / 4096.f);
  const float rstd = rsqrtf(sq * (1.f / 4096.f) - mu * mu + 1e-5f);

  const int c = t >> 5;
  const int p0 = (8 * t) & 255;
  const float sev = se[n * 16 + c];
  const float sc = rstd * gn_w[c] * sev;
  const float of = (gn_b[c] - mu * rstd * gn_w[c]) * sev;
  #pragma unroll
  for (int k = 0; k < 8; ++k) Hl[(p0 + k) * 24 + c] = f2bf(v[k] * sc + of);
  __syncthreads();

  const int cl = lane & 31, h = lane >> 5;
  const int px = cl & 15, y0 = 2 * w + (cl >> 4);
  vf16 acc[4];
  #pragma unroll
  for (int nt = 0; nt < 4; ++nt) acc[nt] = (vf16)0.f;
  for (int e = 0; e < 9; ++e) {
    const int dy = e / 3 - 1, dx = e % 3 - 1;
    const int yy = y0 + dy, xx = px + dx;
    const bool ok = (yy >= 0 && yy < 16 && xx >= 0 && xx < 16);
    const int ps = ok ? yy * 16 + xx : 0;
    vs8 a = *(const vs8*)&Hl[ps * 24 + h * 8];
    if (!ok) a = (vs8)(short)0;
    #pragma unroll
    for (int nt = 0; nt < 4; ++nt) {
      vs8 bf = *(const vs8*)&Wp[(e * 128 + nt * 32 + cl) * 24 + h * 8];
      acc[nt] = __builtin_amdgcn_mfma_f32_32x32x16_bf16(a, bf, acc[nt], 0, 0, 0);
    }
  }
  float* op = out + n * 32768;
  #pragma unroll
  for (int nt = 0; nt < 4; ++nt) {
    const int co = nt * 32 + cl;
    const float bv = pb[co];
    #pragma unroll
    for (int rq = 0; rq < 4; ++rq) {
      vf4 vv;
      #pragma unroll
      for (int j = 0; j < 4; ++j) vv[j] = acc[nt][rq * 4 + j] + bv;
      *(vf4*)&op[co * 256 + 32 * w + 8 * rq + 4 * h] = vv;
    }
  }
}

// ---------------------------------------------------------------------------
// Dual-component Chebyshev(NCHEB)-PCG (R15's verified math) with
// __launch_bounds__(64, 1): min 1 wave/EU lets the allocator use up to 512
// VGPRs, so the doubled live state stays in registers (R15 spilled at the
// default 256 cap). One wave interleaves both independent 512-node components
// of a system, hiding shuffle/FMA latency. 16 blocks, 1 wave each.
// ---------------------------------------------------------------------------
__global__ __launch_bounds__(64, 1) void k_pcg(
    const float* __restrict__ att, const float* __restrict__ grad,
    float* __restrict__ sol, int maxit, float tol2) {
  const int sys = blockIdx.x;          // 16 blocks
  const int l = threadIdx.x & 63;
  const int row = l & 15;
  const int c4 = l >> 4;
  const int i0 = 16 * row + 4 * c4;

  const int n = sys >> 2, g = sys & 3;
  const float* ab = att + (n * 40 + g * 10) * 256;
  const float* gb = grad + (n * 40 + g * 10) * 256;

  const int ERA[2] = {4, 8}, EDA[2] = {9, 5};
  const int ERB[2] = {2, 6}, EDB[2] = {7, 3};
  const int EC[2]  = {0, 1};
  const int FA[2]  = {0, 1}, FB[2] = {2, 3};

  auto L4 = [](const float* p) { return *reinterpret_cast<const float4*>(p); };
  auto unp = [](float4 v, float* o) { o[0] = v.x; o[1] = v.y; o[2] = v.z; o[3] = v.w; };

  float wLa[2][4], wRa[2][4], wUa[2][4], wDa[2][4], wXa[2][4], dga[2][4], iva[2][4], rsa[2][4];
  float wLb[2][4], wRb[2][4], wUb[2][4], wDb[2][4], wXb[2][4], dgb[2][4], ivb[2][4], rsb[2][4];

  #pragma unroll
  for (int c = 0; c < 2; ++c) {
    // ---- field a ----
    float rA[4], gA[4], dA[4], hA[4], uA[4] = {0,0,0,0}, vA[4] = {0,0,0,0};
    unp(L4(ab + ERA[c] * 256 + i0), rA); unp(L4(gb + ERA[c] * 256 + i0), gA);
    unp(L4(ab + EDA[c] * 256 + i0), dA); unp(L4(gb + EDA[c] * 256 + i0), hA);
    if (row > 0) { unp(L4(ab + EDA[c] * 256 + i0 - 16), uA); unp(L4(gb + EDA[c] * 256 + i0 - 16), vA); }
    float rlA = (l > 0) ? ab[ERA[c] * 256 + i0 - 1] : 0.f;
    float glA = (l > 0) ? gb[ERA[c] * 256 + i0 - 1] : 0.f;
    float cX[4], gX[4], cU[4] = {0,0,0,0}, gU[4] = {0,0,0,0};
    unp(L4(ab + EC[c] * 256 + i0), cX); unp(L4(gb + EC[c] * 256 + i0), gX);
    float clX = 0.f, glX = 0.f;
    if (c == 0) { if (l > 0) { clX = ab[EC[c] * 256 + i0 - 1]; glX = gb[EC[c] * 256 + i0 - 1]; } }
    else if (row > 0) { unp(L4(ab + EC[c] * 256 + i0 - 16), cU); unp(L4(gb + EC[c] * 256 + i0 - 16), gU); }

    #pragma unroll
    for (int k = 0; k < 4; ++k) {
      wRa[c][k] = (k < 3 || c4 < 3) ? rA[k] * rA[k] : 0.f;
      wLa[c][k] = (k > 0) ? rA[k-1] * rA[k-1] : ((c4 > 0) ? rlA * rlA : 0.f);
      wDa[c][k] = (row < 15) ? dA[k] * dA[k] : 0.f;
      wUa[c][k] = (row > 0) ? uA[k] * uA[k] : 0.f;
      float rhs = wRa[c][k] * gA[k] - wLa[c][k] * ((k > 0) ? gA[k-1] : glA)
                + wDa[c][k] * hA[k] - wUa[c][k] * vA[k];
      float wx, gx;
      if (c == 0) {
        wx = (k > 0) ? cX[k-1] * cX[k-1] : ((c4 > 0) ? clX * clX : 0.f);
        gx = (k > 0) ? gX[k-1] : glX;
      } else {
        wx = (row > 0) ? cU[k] * cU[k] : 0.f;
        gx = gU[k];
      }
      wXa[c][k] = wx;
      rhs -= wx * gx;
      rsa[c][k] = rhs;
      dga[c][k] = 1e-12f + wRa[c][k] + wLa[c][k] + wDa[c][k] + wUa[c][k] + wx;
    }

    // ---- field b ----
    float rB[4], gB[4], dB[4], hB[4], uB[4] = {0,0,0,0}, vB[4] = {0,0,0,0};
    unp(L4(ab + ERB[c] * 256 + i0), rB); unp(L4(gb + ERB[c] * 256 + i0), gB);
    unp(L4(ab + EDB[c] * 256 + i0), dB); unp(L4(gb + EDB[c] * 256 + i0), hB);
    if (row > 0) { unp(L4(ab + EDB[c] * 256 + i0 - 16), uB); unp(L4(gb + EDB[c] * 256 + i0 - 16), vB); }
    float rlB = (l > 0) ? ab[ERB[c] * 256 + i0 - 1] : 0.f;
    float glB = (l > 0) ? gb[ERB[c] * 256 + i0 - 1] : 0.f;

    #pragma unroll
    for (int k = 0; k < 4; ++k) {
      wRb[c][k] = (k < 3 || c4 < 3) ? rB[k] * rB[k] : 0.f;
      wLb[c][k] = (k > 0) ? rB[k-1] * rB[k-1] : ((c4 > 0) ? rlB * rlB : 0.f);
      wDb[c][k] = (row < 15) ? dB[k] * dB[k] : 0.f;
      wUb[c][k] = (row > 0) ? uB[k] * uB[k] : 0.f;
      float wx;
      if (c == 0) wx = (k < 3 || c4 < 3) ? cX[k] * cX[k] : 0.f;
      else        wx = (row < 15) ? cX[k] * cX[k] : 0.f;
      wXb[c][k] = wx;
      rsb[c][k] = wRb[c][k] * gB[k] - wLb[c][k] * ((k > 0) ? gB[k-1] : glB)
                + wDb[c][k] * hB[k] - wUb[c][k] * vB[k]
                + wx * gX[k];
      dgb[c][k] = 1e-12f + wRb[c][k] + wLb[c][k] + wDb[c][k] + wUb[c][k] + wx;
    }

    if (l == 63) {  // anchors at pixel 255
      float wr = rA[3] * rA[3], wd = dA[3] * dA[3];
      dga[c][3] += wr + wd;
      rsa[c][3] += wr * gA[3] + wd * hA[3];
      float wc = cX[3] * cX[3], wrb = rB[3] * rB[3], wdb = dB[3] * dB[3];
      dgb[c][3] += wc + wrb + wdb;
      rsb[c][3] += wc * gX[3] + wrb * gB[3] + wdb * hB[3];
    }
  }
  #pragma unroll
  for (int c = 0; c < 2; ++c)
    #pragma unroll
    for (int k = 0; k < 4; ++k) { iva[c][k] = 1.f / dga[c][k]; ivb[c][k] = 1.f / dgb[c][k]; }

  float ua[2][4], ub[2][4], wa[2][4], wb[2][4];

  auto spmv = [&](const float (&ia_)[2][4], const float (&ib_)[2][4],
                  float (&oa)[2][4], float (&ob)[2][4]) {
    float aL[2], aR[2], bL[2], bR[2];
    #pragma unroll
    for (int c = 0; c < 2; ++c) {
      aL[c] = __shfl_up(ia_[c][3], 16, 64);
      aR[c] = __shfl_down(ia_[c][0], 16, 64);
      bL[c] = __shfl_up(ib_[c][3], 16, 64);
      bR[c] = __shfl_down(ib_[c][0], 16, 64);
    }
    #pragma unroll
    for (int c = 0; c < 2; ++c) {
      float aU[4], aD[4], bU[4], bD[4];
      #pragma unroll
      for (int k = 0; k < 4; ++k) {
        aU[k] = dppf<0x138>(ia_[c][k]);
        aD[k] = dppf<0x130>(ia_[c][k]);
        bU[k] = dppf<0x138>(ib_[c][k]);
        bD[k] = dppf<0x130>(ib_[c][k]);
      }
      float uaL[4] = {aL[c], ia_[c][0], ia_[c][1], ia_[c][2]};
      float uaR[4] = {ia_[c][1], ia_[c][2], ia_[c][3], aR[c]};
      float ubL[4] = {bL[c], ib_[c][0], ib_[c][1], ib_[c][2]};
      float ubR[4] = {ib_[c][1], ib_[c][2], ib_[c][3], bR[c]};
      #pragma unroll
      for (int k = 0; k < 4; ++k) {
        float cA = (c == 0) ? ubL[k] : bU[k];
        float cB = (c == 0) ? uaR[k] : aD[k];
        oa[c][k] = dga[c][k] * ia_[c][k] - wLa[c][k] * uaL[k] - wRa[c][k] * uaR[k]
                 - wUa[c][k] * aU[k] - wDa[c][k] * aD[k] - wXa[c][k] * cA;
        ob[c][k] = dgb[c][k] * ib_[c][k] - wLb[c][k] * ubL[k] - wRb[c][k] * ubR[k]
                 - wUb[c][k] * bU[k] - wDb[c][k] * bD[k] - wXb[c][k] * cB;
      }
    }
  };

  constexpr float lo = 0.01f, hi = 2.0f;
  constexpr float th = (hi + lo) * 0.5f, dl = (hi - lo) * 0.5f, s1 = th / dl;

  float xa[2][4], xb[2][4], ra_[2][4], rb_[2][4];
  float pa[2][4], pb_[2][4], sa[2][4], sb[2][4];
  #pragma unroll
  for (int c = 0; c < 2; ++c)
    #pragma unroll
    for (int k = 0; k < 4; ++k) {
      xa[c][k] = 0.f; xb[c][k] = 0.f;
      pa[c][k] = 0.f; pb_[c][k] = 0.f;
      sa[c][k] = 0.f; sb[c][k] = 0.f;
      ra_[c][k] = rsa[c][k]; rb_[c][k] = rsb[c][k];
    }

  auto cheb = [&]() {
    float da_[2][4], db_[2][4], ta[2][4], tb[2][4], qa[2][4], qb[2][4];
    #pragma unroll
    for (int c = 0; c < 2; ++c)
      #pragma unroll
      for (int k = 0; k < 4; ++k) {
        da_[c][k] = (1.0f / th) * iva[c][k] * ra_[c][k];
        db_[c][k] = (1.0f / th) * ivb[c][k] * rb_[c][k];
        ua[c][k] = da_[c][k]; ub[c][k] = db_[c][k];
      }
    spmv(da_, db_, ta, tb);
    #pragma unroll
    for (int c = 0; c < 2; ++c)
      #pragma unroll
      for (int k = 0; k < 4; ++k) {
        wa[c][k] = ta[c][k]; wb[c][k] = tb[c][k];
        qa[c][k] = ra_[c][k] - ta[c][k]; qb[c][k] = rb_[c][k] - tb[c][k];
      }
    float rho = 1.0f / s1;
    #pragma unroll
    for (int j = 1; j < NCHEB; ++j) {
      float rho2 = 1.0f / (2.0f * s1 - rho);
      float c1 = rho2 * rho, c2 = 2.0f * rho2 / dl;
      #pragma unroll
      for (int c = 0; c < 2; ++c)
        #pragma unroll
        for (int k = 0; k < 4; ++k) {
          da_[c][k] = c1 * da_[c][k] + c2 * iva[c][k] * qa[c][k];
          db_[c][k] = c1 * db_[c][k] + c2 * ivb[c][k] * qb[c][k];
          ua[c][k] += da_[c][k]; ub[c][k] += db_[c][k];
        }
      spmv(da_, db_, ta, tb);
      #pragma unroll
      for (int c = 0; c < 2; ++c)
        #pragma unroll
        for (int k = 0; k < 4; ++k) {
          wa[c][k] += ta[c][k]; wb[c][k] += tb[c][k];
          qa[c][k] -= ta[c][k]; qb[c][k] -= tb[c][k];
        }
      rho = rho2;
    }
  };

  float gamma[2], delta[2];
  auto dots = [&]() {
    float gp[2], dp[2];
    #pragma unroll
    for (int c = 0; c < 2; ++c) {
      gp[c] = 0.f; dp[c] = 0.f;
      #pragma unroll
      for (int k = 0; k < 4; ++k) {
        gp[c] += ra_[c][k] * ua[c][k] + rb_[c][k] * ub[c][k];
        dp[c] += wa[c][k] * ua[c][k] + wb[c][k] * ub[c][k];
      }
    }
    #pragma unroll
    for (int c = 0; c < 2; ++c) {
      gp[c] += dppf<0xB1>(gp[c]);          dp[c] += dppf<0xB1>(dp[c]);
      gp[c] += dppf<0x4E>(gp[c]);          dp[c] += dppf<0x4E>(dp[c]);
      gp[c] += __shfl_xor(gp[c], 4, 64);   dp[c] += __shfl_xor(dp[c], 4, 64);
      gp[c] += dppf<0x128>(gp[c]);         dp[c] += dppf<0x128>(dp[c]);
      gp[c] += __shfl_xor(gp[c], 16, 64);  dp[c] += __shfl_xor(dp[c], 16, 64);
      gp[c] += __shfl_xor(gp[c], 32, 64);  dp[c] += __shfl_xor(dp[c], 32, 64);
      gamma[c] = gp[c]; delta[c] = dp[c];
    }
  };

  cheb();
  dots();
  float thresh[2], gamma_old[2], alpha_old[2];
  #pragma unroll
  for (int c = 0; c < 2; ++c) { thresh[c] = tol2 * gamma[c]; gamma_old[c] = gamma[c]; alpha_old[c] = 1.f; }

  for (int it = 0; it < maxit && (gamma[0] > thresh[0] || gamma[1] > thresh[1]); ++it) {
    float alpha[2], beta[2];
    #pragma unroll
    for (int c = 0; c < 2; ++c) {
      beta[c] = (it == 0) ? 0.f : gamma[c] / gamma_old[c];
      alpha[c] = (it == 0) ? gamma[c] / delta[c]
                           : gamma[c] / (delta[c] - beta[c] * gamma[c] / alpha_old[c]);
    }
    #pragma unroll
    for (int c = 0; c < 2; ++c)
      #pragma unroll
      for (int k = 0; k < 4; ++k) {
        pa[c][k] = ua[c][k] + beta[c] * pa[c][k];   pb_[c][k] = ub[c][k] + beta[c] * pb_[c][k];
        sa[c][k] = wa[c][k] + beta[c] * sa[c][k];   sb[c][k] = wb[c][k] + beta[c] * sb[c][k];
        xa[c][k] += alpha[c] * pa[c][k];            xb[c][k] += alpha[c] * pb_[c][k];
        ra_[c][k] -= alpha[c] * sa[c][k];           rb_[c][k] -= alpha[c] * sb[c][k];
      }
    #pragma unroll
    for (int c = 0; c < 2; ++c) { gamma_old[c] = gamma[c]; alpha_old[c] = alpha[c]; }
    cheb();
    dots();
  }

  float4* sol4 = reinterpret_cast<float4*>(sol);
  const int slot = 4 * row + c4;
  #pragma unroll
  for (int c = 0; c < 2; ++c) {
    sol4[sys * 256 + FA[c] * 64 + slot] = make_float4(xa[c][0], xa[c][1], xa[c][2], xa[c][3]);
    sol4[sys * 256 + FB[c] * 64 + slot] = make_float4(xb[c][0], xb[c][1], xb[c][2], xb[c][3]);
  }
}

extern "C" void kernel_launch(void* const* d_in, const int* in_sizes, int n_in,
                              void* d_out, int out_size, void* d_ws, size_t ws_size,
                              hipStream_t stream) {
  const float* x       = (const float*)d_in[0];
  const float* grad_w1 = (const float*)d_in[1];
  const float* grad_b1 = (const float*)d_in[2];
  const float* grad_w2 = (const float*)d_in[3];
  const float* grad_b2 = (const float*)d_in[4];
  const float* att_w1  = (const float*)d_in[5];
  const float* att_b1  = (const float*)d_in[6];
  const float* att_w2  = (const float*)d_in[7];
  const float* att_b2  = (const float*)d_in[8];
  const float* se_w1   = (const float*)d_in[9];
  const float* se_b1   = (const float*)d_in[10];
  const float* se_w2   = (const float*)d_in[11];
  const float* se_b2   = (const float*)d_in[12];
  const float* gn_w    = (const float*)d_in[13];
  const float* gn_b    = (const float*)d_in[14];
  const float* post_w  = (const float*)d_in[15];
  const float* post_b  = (const float*)d_in[16];
  float* out = (float*)d_out;
  float* ws = (float*)d_ws;

  float* t1    = ws;                // 65536 (grad conv1 out)
  float* t2    = ws + 65536;        // 65536 (att conv1 out)
  float* gradb = ws + 131072;       // 40960
  float* attb  = ws + 172032;       // 40960
  float* seb   = ws + 212992;       // 64
  float* solb  = ws;                // 16384 (reuses t1 after conv2)

  // conv1: 2 branches x 4 images x 4 co-tiles = 32 blocks + 4 SE blocks
  k_conv<64, 4, true><<<36, 256, 0, stream>>>(
      x, x, grad_w1, grad_b1, att_w1, att_b1, t1, t2, 1, 1,
      x, se_w1, se_b1, se_w2, se_b2, seb);
  // conv2: 2 x 4 x 3 co-tiles = 24 blocks
  k_conv<40, 3, false><<<24, 256, 0, stream>>>(
      t1, t2, grad_w2, grad_b2, att_w2, att_b2, gradb, attb, 0, 2,
      nullptr, nullptr, nullptr, nullptr, nullptr, nullptr);
  // pcg: 16 blocks x 1 wave, dual-component ILP, up to 512 VGPR (no spill)
  k_pcg<<<16, 64, 0, stream>>>(attb, gradb, solb, 100, 3e-6f);
  k_post<<<4, 512, 0, stream>>>(solb, seb, gn_w, gn_b, post_w, post_b, out);
}

// Round 18
// 98.019 us; speedup vs baseline: 1.2755x; 1.2755x over previous
//
#include <hip/hip_runtime.h>

#define NCHEB 16

typedef __attribute__((ext_vector_type(8))) short vs8;
typedef __attribute__((ext_vector_type(4))) float vf4;
typedef __attribute__((ext_vector_type(16))) float vf16;

__device__ __forceinline__ unsigned short f2bf(float f) {
  union { float f; unsigned int u; } x; x.f = f;
  unsigned int r = (x.u + 0x7FFFu + ((x.u >> 16) & 1u)) >> 16;
  return (unsigned short)r;
}

// DPP move: 0x138 = wave_shr:1, 0x130 = wave_shl:1, 0xB1 = quad_perm xor1,
// 0x4E = quad_perm xor2, 0x128 = row_ror:8 (xor8 within 16-lane rows).
template<int CTRL>
__device__ __forceinline__ float dppf(float x) {
  return __int_as_float(__builtin_amdgcn_mov_dpp(__float_as_int(x), CTRL, 0xF, 0xF, true));
}

// Point-to-point release/acquire flags (64B-strided lines, zeroed per launch).
__device__ __forceinline__ void flag_set(unsigned* f) {
  __builtin_amdgcn_fence(__ATOMIC_RELEASE, "agent");
  __hip_atomic_store(f, 1u, __ATOMIC_RELAXED, __HIP_MEMORY_SCOPE_AGENT);
}
__device__ __forceinline__ void flag_wait(unsigned* f) {
  while (__hip_atomic_load(f, __ATOMIC_RELAXED, __HIP_MEMORY_SCOPE_AGENT) == 0u)
    __builtin_amdgcn_s_sleep(2);
}

// ---------------------------------------------------------------------------
// MFMA 3x3 SAME conv, co-tile split (R13's proven kernel, unchanged).
// ---------------------------------------------------------------------------
template<int COUT, int TILES, bool SE>
__global__ __launch_bounds__(256) void k_conv(
    const float* __restrict__ inA, const float* __restrict__ inB,
    const float* __restrict__ wA, const float* __restrict__ bA,
    const float* __restrict__ wB, const float* __restrict__ bB,
    float* __restrict__ outA, float* __restrict__ outB,
    int actA, int actB,
    const float* __restrict__ x,
    const float* __restrict__ sw1, const float* __restrict__ sb1,
    const float* __restrict__ sw2, const float* __restrict__ sb2,
    float* __restrict__ seo) {
  __shared__ unsigned short Xl[256 * 64];
  __shared__ unsigned short Wl[9 * 16 * 64];
  __shared__ float sp[64];
  __shared__ float sh1[32];
  const int b = blockIdx.x;
  const int t = threadIdx.x;

  if (SE && b >= 8 * TILES) {
    const int n = b - 8 * TILES;
    const int c = t >> 2, part = t & 3;
    const float* xp = x + (n * 64 + c) * 256 + part * 64;
    float s = 0.f;
    for (int k = 0; k < 64; ++k) s += xp[k];
    s += __shfl_xor(s, 1, 64);
    s += __shfl_xor(s, 2, 64);
    if (part == 0) sp[c] = s * (1.f / 256.f);
    __syncthreads();
    if (t < 32) {
      float a = sb1[t];
      for (int k = 0; k < 64; ++k) a += sw1[t * 64 + k] * sp[k];
      sh1[t] = a > 0.f ? a : 0.01f * a;
    }
    __syncthreads();
    if (t < 16) {
      float a = sb2[t];
      for (int k = 0; k < 32; ++k) a += sw2[t * 32 + k] * sh1[k];
      seo[n * 16 + t] = 1.f / (1.f + __expf(-a));
    }
    return;
  }

  const int n = b & 3;
  const int q = b >> 2;
  const int br = (q >= TILES) ? 1 : 0;
  const int ct = q - br * TILES;
  const int co0 = ct * 16;
  const float* inp = (br ? inB : inA) + n * 64 * 256;
  const float* wsrc = br ? wB : wA;
  const float* bias = br ? bB : bA;
  float* outp = (br ? outB : outA) + n * COUT * 256;
  const int act = br ? actB : actA;

  {
    const int p = t;
    #pragma unroll
    for (int q8 = 0; q8 < 8; ++q8) {
      vs8 v;
      #pragma unroll
      for (int j = 0; j < 8; ++j) v[j] = (short)f2bf(inp[(8 * q8 + j) * 256 + p]);
      *(vs8*)&Xl[p * 64 + ((q8 ^ (p & 7)) << 3)] = v;
    }
  }
  {
    const int col = t >> 4;
    const int sub = t & 15;
    const int co = co0 + col;
    if (co < COUT) {
      const float* wp = wsrc + (co * 64 + sub * 4) * 9;
      #pragma unroll
      for (int cc = 0; cc < 4; ++cc) {
        const int ci = sub * 4 + cc;
        #pragma unroll
        for (int e = 0; e < 9; ++e)
          Wl[(e * 16 + col) * 64 + (ci ^ ((col & 7) << 3))] = f2bf(wp[cc * 9 + e]);
      }
    } else {
      #pragma unroll
      for (int cc = 0; cc < 4; ++cc) {
        const int ci = sub * 4 + cc;
        #pragma unroll
        for (int e = 0; e < 9; ++e)
          Wl[(e * 16 + col) * 64 + (ci ^ ((col & 7) << 3))] = 0;
      }
    }
  }
  __syncthreads();

  const int w = t >> 6, lane = t & 63;
  const int px = lane & 15, kg = lane >> 4;
  vf4 acc[4];
  #pragma unroll
  for (int mt = 0; mt < 4; ++mt) acc[mt] = (vf4)0.f;

  for (int e = 0; e < 9; ++e) {
    const int dy = e / 3 - 1, dx = e % 3 - 1;
    const bool xok = (dx == 0) || (dx < 0 ? (px > 0) : (px < 15));
    const int xoff = xok ? dx : 0;
    #pragma unroll
    for (int ks = 0; ks < 2; ++ks) {
      vs8 bf = *(const vs8*)&Wl[(e * 16 + px) * 64 + (((ks * 4 + kg) ^ (px & 7)) << 3)];
      #pragma unroll
      for (int mt = 0; mt < 4; ++mt) {
        const int yy = 4 * w + mt + dy;
        if (yy < 0 || yy > 15) continue;
        const int ps = yy * 16 + px + xoff;
        vs8 a = *(const vs8*)&Xl[ps * 64 + (((ks * 4 + kg) ^ (ps & 7)) << 3)];
        if (!xok) a = (vs8)(short)0;
        acc[mt] = __builtin_amdgcn_mfma_f32_16x16x32_bf16(a, bf, acc[mt], 0, 0, 0);
      }
    }
  }

  const int co = co0 + px;
  if (co < COUT) {
    const float bv = bias[co];
    #pragma unroll
    for (int mt = 0; mt < 4; ++mt) {
      const int y = 4 * w + mt;
      vf4 v = acc[mt];
      #pragma unroll
      for (int j = 0; j < 4; ++j) {
        float s = v[j] + bv;
        if (act == 1) s = s > 0.f ? s : 0.01f * s;
        else if (act == 2) s = 1.f / (1.f + __expf(-s));
        v[j] = s;
      }
      *(vf4*)&outp[co * 256 + y * 16 + kg * 4] = v;
    }
  }
}

// ---------------------------------------------------------------------------
// Wave-local Chebyshev(NCHEB=16)-PCG, DPP SpMV (R13's verified math; only
// NCHEB changed 8->16: same stable recurrence, fewer outer iterations for
// the same total SpMV budget).
// ---------------------------------------------------------------------------
__device__ void pcg_unit(
    int unit, const float* __restrict__ att, const float* __restrict__ grad,
    float* __restrict__ sol, int maxit, float tol2) {
  const int sys = unit >> 1;
  const int wv = unit & 1;
  const int l = threadIdx.x & 63;
  const int row = l & 15;
  const int c4 = l >> 4;
  const int i0 = 16 * row + 4 * c4;

  const int n = sys >> 2, g = sys & 3;
  const float* ab = att + (n * 40 + g * 10) * 256;
  const float* gb = grad + (n * 40 + g * 10) * 256;

  int era, eda, erb, edb, ec, fa, fb;
  if (wv == 0) { fa = 0; fb = 2; era = 4; eda = 9; erb = 2; edb = 7; ec = 0; }
  else         { fa = 1; fb = 3; era = 8; eda = 5; erb = 6; edb = 3; ec = 1; }

  auto L4 = [](const float* p) { return *reinterpret_cast<const float4*>(p); };
  auto unp = [](float4 v, float* o) { o[0] = v.x; o[1] = v.y; o[2] = v.z; o[3] = v.w; };

  float wLa[4], wRa[4], wUa[4], wDa[4], wXa[4], dga[4], iva[4], rsa[4];
  float wLb[4], wRb[4], wUb[4], wDb[4], wXb[4], dgb[4], ivb[4], rsb[4];

  float rA[4], gA[4], dA[4], hA[4], uA[4] = {0,0,0,0}, vA[4] = {0,0,0,0};
  unp(L4(ab + era * 256 + i0), rA); unp(L4(gb + era * 256 + i0), gA);
  unp(L4(ab + eda * 256 + i0), dA); unp(L4(gb + eda * 256 + i0), hA);
  if (row > 0) { unp(L4(ab + eda * 256 + i0 - 16), uA); unp(L4(gb + eda * 256 + i0 - 16), vA); }
  float rlA = (l > 0) ? ab[era * 256 + i0 - 1] : 0.f;
  float glA = (l > 0) ? gb[era * 256 + i0 - 1] : 0.f;
  float cX[4], gX[4], cU[4] = {0,0,0,0}, gU[4] = {0,0,0,0};
  unp(L4(ab + ec * 256 + i0), cX); unp(L4(gb + ec * 256 + i0), gX);
  float clX = 0.f, glX = 0.f;
  if (wv == 0) { if (l > 0) { clX = ab[ec * 256 + i0 - 1]; glX = gb[ec * 256 + i0 - 1]; } }
  else if (row > 0) { unp(L4(ab + ec * 256 + i0 - 16), cU); unp(L4(gb + ec * 256 + i0 - 16), gU); }

  #pragma unroll
  for (int k = 0; k < 4; ++k) {
    wRa[k] = (k < 3 || c4 < 3) ? rA[k] * rA[k] : 0.f;
    wLa[k] = (k > 0) ? rA[k-1] * rA[k-1] : ((c4 > 0) ? rlA * rlA : 0.f);
    wDa[k] = (row < 15) ? dA[k] * dA[k] : 0.f;
    wUa[k] = (row > 0) ? uA[k] * uA[k] : 0.f;
    float rhs = wRa[k] * gA[k] - wLa[k] * ((k > 0) ? gA[k-1] : glA)
              + wDa[k] * hA[k] - wUa[k] * vA[k];
    float wx, gx;
    if (wv == 0) {
      wx = (k > 0) ? cX[k-1] * cX[k-1] : ((c4 > 0) ? clX * clX : 0.f);
      gx = (k > 0) ? gX[k-1] : glX;
    } else {
      wx = (row > 0) ? cU[k] * cU[k] : 0.f;
      gx = gU[k];
    }
    wXa[k] = wx;
    rhs -= wx * gx;
    rsa[k] = rhs;
    dga[k] = 1e-12f + wRa[k] + wLa[k] + wDa[k] + wUa[k] + wx;
  }

  float rB[4], gB[4], dB[4], hB[4], uB[4] = {0,0,0,0}, vB[4] = {0,0,0,0};
  unp(L4(ab + erb * 256 + i0), rB); unp(L4(gb + erb * 256 + i0), gB);
  unp(L4(ab + edb * 256 + i0), dB); unp(L4(gb + edb * 256 + i0), hB);
  if (row > 0) { unp(L4(ab + edb * 256 + i0 - 16), uB); unp(L4(gb + edb * 256 + i0 - 16), vB); }
  float rlB = (l > 0) ? ab[erb * 256 + i0 - 1] : 0.f;
  float glB = (l > 0) ? gb[erb * 256 + i0 - 1] : 0.f;

  #pragma unroll
  for (int k = 0; k < 4; ++k) {
    wRb[k] = (k < 3 || c4 < 3) ? rB[k] * rB[k] : 0.f;
    wLb[k] = (k > 0) ? rB[k-1] * rB[k-1] : ((c4 > 0) ? rlB * rlB : 0.f);
    wDb[k] = (row < 15) ? dB[k] * dB[k] : 0.f;
    wUb[k] = (row > 0) ? uB[k] * uB[k] : 0.f;
    float wx;
    if (wv == 0) wx = (k < 3 || c4 < 3) ? cX[k] * cX[k] : 0.f;
    else         wx = (row < 15) ? cX[k] * cX[k] : 0.f;
    wXb[k] = wx;
    rsb[k] = wRb[k] * gB[k] - wLb[k] * ((k > 0) ? gB[k-1] : glB)
           + wDb[k] * hB[k] - wUb[k] * vB[k]
           + wx * gX[k];
    dgb[k] = 1e-12f + wRb[k] + wLb[k] + wDb[k] + wUb[k] + wx;
  }

  if (l == 63) {
    float wr = rA[3] * rA[3], wd = dA[3] * dA[3];
    dga[3] += wr + wd;
    rsa[3] += wr * gA[3] + wd * hA[3];
    float wc = cX[3] * cX[3], wrb = rB[3] * rB[3], wdb = dB[3] * dB[3];
    dgb[3] += wc + wrb + wdb;
    rsb[3] += wc * gX[3] + wrb * gB[3] + wdb * hB[3];
  }
  #pragma unroll
  for (int k = 0; k < 4; ++k) { iva[k] = 1.f / dga[k]; ivb[k] = 1.f / dgb[k]; }

  float ua[4], ub[4], wa[4], wb[4];

  auto spmv = [&](const float (&ia_)[4], const float (&ib_)[4],
                  float (&oa)[4], float (&ob)[4]) {
    float aL = __shfl_up(ia_[3], 16, 64);
    float aR = __shfl_down(ia_[0], 16, 64);
    float bL = __shfl_up(ib_[3], 16, 64);
    float bR = __shfl_down(ib_[0], 16, 64);
    float aU[4], aD[4], bU[4], bD[4];
    #pragma unroll
    for (int k = 0; k < 4; ++k) {
      aU[k] = dppf<0x138>(ia_[k]);
      aD[k] = dppf<0x130>(ia_[k]);
      bU[k] = dppf<0x138>(ib_[k]);
      bD[k] = dppf<0x130>(ib_[k]);
    }
    float uaL[4] = {aL, ia_[0], ia_[1], ia_[2]};
    float uaR[4] = {ia_[1], ia_[2], ia_[3], aR};
    float ubL[4] = {bL, ib_[0], ib_[1], ib_[2]};
    float ubR[4] = {ib_[1], ib_[2], ib_[3], bR};
    #pragma unroll
    for (int k = 0; k < 4; ++k) {
      float cA = (wv == 0) ? ubL[k] : bU[k];
      float cB = (wv == 0) ? uaR[k] : aD[k];
      oa[k] = dga[k] * ia_[k] - wLa[k] * uaL[k] - wRa[k] * uaR[k]
            - wUa[k] * aU[k] - wDa[k] * aD[k] - wXa[k] * cA;
      ob[k] = dgb[k] * ib_[k] - wLb[k] * ubL[k] - wRb[k] * ubR[k]
            - wUb[k] * bU[k] - wDb[k] * bD[k] - wXb[k] * cB;
    }
  };

  constexpr float lo = 0.01f, hi = 2.0f;
  constexpr float th = (hi + lo) * 0.5f, dl = (hi - lo) * 0.5f, s1 = th / dl;

  float xa[4] = {0,0,0,0}, xb[4] = {0,0,0,0};
  float ra_[4], rb_[4], pa[4] = {0,0,0,0}, pb_[4] = {0,0,0,0};
  float sa[4] = {0,0,0,0}, sb[4] = {0,0,0,0};
  #pragma unroll
  for (int k = 0; k < 4; ++k) { ra_[k] = rsa[k]; rb_[k] = rsb[k]; }

  auto cheb = [&]() {
    float da_[4], db_[4], ta[4], tb[4], qa[4], qb[4];
    #pragma unroll
    for (int k = 0; k < 4; ++k) {
      da_[k] = (1.0f / th) * iva[k] * ra_[k];
      db_[k] = (1.0f / th) * ivb[k] * rb_[k];
      ua[k] = da_[k]; ub[k] = db_[k];
    }
    spmv(da_, db_, ta, tb);
    #pragma unroll
    for (int k = 0; k < 4; ++k) {
      wa[k] = ta[k]; wb[k] = tb[k];
      qa[k] = ra_[k] - ta[k]; qb[k] = rb_[k] - tb[k];
    }
    float rho = 1.0f / s1;
    #pragma unroll
    for (int j = 1; j < NCHEB; ++j) {
      float rho2 = 1.0f / (2.0f * s1 - rho);
      float c1 = rho2 * rho, c2 = 2.0f * rho2 / dl;
      #pragma unroll
      for (int k = 0; k < 4; ++k) {
        da_[k] = c1 * da_[k] + c2 * iva[k] * qa[k];
        db_[k] = c1 * db_[k] + c2 * ivb[k] * qb[k];
        ua[k] += da_[k]; ub[k] += db_[k];
      }
      spmv(da_, db_, ta, tb);
      #pragma unroll
      for (int k = 0; k < 4; ++k) {
        wa[k] += ta[k]; wb[k] += tb[k];
        qa[k] -= ta[k]; qb[k] -= tb[k];
      }
      rho = rho2;
    }
  };

  float gamma, delta;
  auto dots = [&]() {
    float gp = 0.f, dp = 0.f;
    #pragma unroll
    for (int k = 0; k < 4; ++k) {
      gp += ra_[k] * ua[k] + rb_[k] * ub[k];
      dp += wa[k] * ua[k] + wb[k] * ub[k];
    }
    gp += dppf<0xB1>(gp);            dp += dppf<0xB1>(dp);
    gp += dppf<0x4E>(gp);            dp += dppf<0x4E>(dp);
    gp += __shfl_xor(gp, 4, 64);     dp += __shfl_xor(dp, 4, 64);
    gp += dppf<0x128>(gp);           dp += dppf<0x128>(dp);
    gp += __shfl_xor(gp, 16, 64);    dp += __shfl_xor(dp, 16, 64);
    gp += __shfl_xor(gp, 32, 64);    dp += __shfl_xor(dp, 32, 64);
    gamma = gp; delta = dp;
  };

  cheb();
  dots();
  const float thresh = tol2 * gamma;
  float gamma_old = gamma, alpha_old = 1.f;

  for (int it = 0; it < maxit && gamma > thresh; ++it) {
    float beta = (it == 0) ? 0.f : gamma / gamma_old;
    float alpha = (it == 0) ? gamma / delta
                            : gamma / (delta - beta * gamma / alpha_old);
    #pragma unroll
    for (int k = 0; k < 4; ++k) {
      pa[k] = ua[k] + beta * pa[k];   pb_[k] = ub[k] + beta * pb_[k];
      sa[k] = wa[k] + beta * sa[k];   sb[k] = wb[k] + beta * sb[k];
      xa[k] += alpha * pa[k];         xb[k] += alpha * pb_[k];
      ra_[k] -= alpha * sa[k];        rb_[k] -= alpha * sb[k];
    }
    gamma_old = gamma; alpha_old = alpha;
    cheb();
    dots();
  }

  float4* sol4 = reinterpret_cast<float4*>(sol);
  const int slot = 4 * row + c4;
  sol4[sys * 256 + fa * 64 + slot] = make_float4(xa[0], xa[1], xa[2], xa[3]);
  sol4[sys * 256 + fb * 64 + slot] = make_float4(xb[0], xb[1], xb[2], xb[3]);
}

// ---------------------------------------------------------------------------
// k_solve (R14's verified kernel): 32 blocks x 512 thr. Wave 0 = pcg unit.
// Non-leaders flag sol and exit; leaders (bid%8==0) pre-stage post weights on
// waves 1-7 during pcg, join sibling flags, then run GN + SE + post conv.
// ---------------------------------------------------------------------------
__global__ __launch_bounds__(512, 1) void k_solve(
    const float* __restrict__ att, const float* __restrict__ grad,
    const float* __restrict__ se,
    const float* __restrict__ gn_w, const float* __restrict__ gn_b,
    const float* __restrict__ pw, const float* __restrict__ pb,
    float* __restrict__ sol, float* __restrict__ out,
    unsigned* __restrict__ flags, int maxit, float tol2) {
  __shared__ unsigned short Hl[256 * 24];
  __shared__ unsigned short Wp[9 * 128 * 24];
  __shared__ float rs[8], rs2[8];
  const int bid = blockIdx.x;
  const int t = threadIdx.x;
  const bool leader = (bid & 7) == 0;

  if (t < 64) {
    pcg_unit(bid, att, grad, sol, maxit, tol2);   // wave 0
    if (t == 0 && !leader) flag_set(flags + bid * 16);
  } else if (leader) {
    for (int i = t - 64; i < 128 * 16 * 9; i += 448) {
      const int co = i / 144;
      const int rem = i - co * 144;
      const int ci = rem / 9;
      const int e = rem - ci * 9;
      Wp[(e * 128 + co) * 24 + ci] = f2bf(pw[i]);
    }
  }
  if (!leader) return;

  if (t == 0) {
    #pragma unroll
    for (int u = 1; u < 8; ++u) flag_wait(flags + (bid + u) * 16);
    __builtin_amdgcn_fence(__ATOMIC_ACQUIRE, "agent");
  }
  __syncthreads();

  const int n = bid >> 3;
  const int w = t >> 6, lane = t & 63;

  float v[8];
  {
    const vf4* s4 = (const vf4*)(sol + n * 4096 + 8 * t);
    vf4 a = s4[0], b = s4[1];
    v[0]=a[0];v[1]=a[1];v[2]=a[2];v[3]=a[3];v[4]=b[0];v[5]=b[1];v[6]=b[2];v[7]=b[3];
  }
  float s = 0.f, s2 = 0.f;
  #pragma unroll
  for (int k = 0; k < 8; ++k) { s += v[k]; s2 += v[k] * v[k]; }
  #pragma unroll
  for (int o = 1; o <= 32; o <<= 1) { s += __shfl_xor(s, o, 64); s2 += __shfl_xor(s2, o, 64); }
  if (lane == 0) { rs[w] = s; rs2[w] = s2; }
  __syncthreads();
  float sm = 0.f, sq = 0.f;
  #pragma unroll
  for (int k = 0; k < 8; ++k) { sm += rs[k]; sq += rs2[k]; }
  const float mu = sm * (1.f / 4096.f);
  const float rstd = rsqrtf(sq * (1.f / 4096.f) - mu * mu + 1e-5f);

  const int c = t >> 5;
  const int p0 = (8 * t) & 255;
  const float sev = se[n * 16 + c];
  const float sc = rstd * gn_w[c] * sev;
  const float of = (gn_b[c] - mu * rstd * gn_w[c]) * sev;
  #pragma unroll
  for (int k = 0; k < 8; ++k) Hl[(p0 + k) * 24 + c] = f2bf(v[k] * sc + of);
  __syncthreads();

  const int cl = lane & 31, h = lane >> 5;
  const int px = cl & 15, y0 = 2 * w + (cl >> 4);
  vf16 acc[4];
  #pragma unroll
  for (int nt = 0; nt < 4; ++nt) acc[nt] = (vf16)0.f;
  for (int e = 0; e < 9; ++e) {
    const int dy = e / 3 - 1, dx = e % 3 - 1;
    const int yy = y0 + dy, xx = px + dx;
    const bool ok = (yy >= 0 && yy < 16 && xx >= 0 && xx < 16);
    const int ps = ok ? yy * 16 + xx : 0;
    vs8 a = *(const vs8*)&Hl[ps * 24 + h * 8];
    if (!ok) a = (vs8)(short)0;
    #pragma unroll
    for (int nt = 0; nt < 4; ++nt) {
      vs8 bf = *(const vs8*)&Wp[(e * 128 + nt * 32 + cl) * 24 + h * 8];
      acc[nt] = __builtin_amdgcn_mfma_f32_32x32x16_bf16(a, bf, acc[nt], 0, 0, 0);
    }
  }
  float* op = out + n * 32768;
  #pragma unroll
  for (int nt = 0; nt < 4; ++nt) {
    const int co = nt * 32 + cl;
    const float bv = pb[co];
    #pragma unroll
    for (int rq = 0; rq < 4; ++rq) {
      vf4 vv;
      #pragma unroll
      for (int j = 0; j < 4; ++j) vv[j] = acc[nt][rq * 4 + j] + bv;
      *(vf4*)&op[co * 256 + 32 * w + 8 * rq + 4 * h] = vv;
    }
  }
}

extern "C" void kernel_launch(void* const* d_in, const int* in_sizes, int n_in,
                              void* d_out, int out_size, void* d_ws, size_t ws_size,
                              hipStream_t stream) {
  const float* x       = (const float*)d_in[0];
  const float* grad_w1 = (const float*)d_in[1];
  const float* grad_b1 = (const float*)d_in[2];
  const float* grad_w2 = (const float*)d_in[3];
  const float* grad_b2 = (const float*)d_in[4];
  const float* att_w1  = (const float*)d_in[5];
  const float* att_b1  = (const float*)d_in[6];
  const float* att_w2  = (const float*)d_in[7];
  const float* att_b2  = (const float*)d_in[8];
  const float* se_w1   = (const float*)d_in[9];
  const float* se_b1   = (const float*)d_in[10];
  const float* se_w2   = (const float*)d_in[11];
  const float* se_b2   = (const float*)d_in[12];
  const float* gn_w    = (const float*)d_in[13];
  const float* gn_b    = (const float*)d_in[14];
  const float* post_w  = (const float*)d_in[15];
  const float* post_b  = (const float*)d_in[16];
  float* out = (float*)d_out;
  float* ws = (float*)d_ws;

  float* t1    = ws;                // 65536 (grad conv1 out)
  float* t2    = ws + 65536;        // 65536 (att conv1 out)
  float* gradb = ws + 131072;       // 40960
  float* attb  = ws + 172032;       // 40960
  float* seb   = ws + 212992;       // 64
  float* solb  = ws + 213056;       // 16384
  unsigned* flags = (unsigned*)(ws + 230000); // 32 x 64B = 2 KB

  hipMemsetAsync(flags, 0, 2048, stream);
  // conv1: 2 branches x 4 images x 4 co-tiles = 32 blocks + 4 SE blocks
  k_conv<64, 4, true><<<36, 256, 0, stream>>>(
      x, x, grad_w1, grad_b1, att_w1, att_b1, t1, t2, 1, 1,
      x, se_w1, se_b1, se_w2, se_b2, seb);
  // conv2: 2 x 4 x 3 co-tiles = 24 blocks
  k_conv<40, 3, false><<<24, 256, 0, stream>>>(
      t1, t2, grad_w2, grad_b2, att_w2, att_b2, gradb, attb, 0, 2,
      nullptr, nullptr, nullptr, nullptr, nullptr, nullptr);
  // solve: pcg (NCHEB=16, fewer outers) + GN + SE + post conv, one dispatch
  k_solve<<<32, 512, 0, stream>>>(
      attb, gradb, seb, gn_w, gn_b, post_w, post_b,
      solb, out, flags, 40, 3e-6f);
}

// Round 19
// 97.910 us; speedup vs baseline: 1.2770x; 1.0011x over previous
//
#include <hip/hip_runtime.h>

#define NCHEB 16

typedef __attribute__((ext_vector_type(8))) short vs8;
typedef __attribute__((ext_vector_type(4))) float vf4;
typedef __attribute__((ext_vector_type(16))) float vf16;

__device__ __forceinline__ unsigned short f2bf(float f) {
  union { float f; unsigned int u; } x; x.f = f;
  unsigned int r = (x.u + 0x7FFFu + ((x.u >> 16) & 1u)) >> 16;
  return (unsigned short)r;
}

// DPP move: 0x138 = wave_shr:1, 0x130 = wave_shl:1, 0xB1 = quad_perm xor1,
// 0x4E = quad_perm xor2, 0x128 = row_ror:8 (xor8 within 16-lane rows).
template<int CTRL>
__device__ __forceinline__ float dppf(float x) {
  return __int_as_float(__builtin_amdgcn_mov_dpp(__float_as_int(x), CTRL, 0xF, 0xF, true));
}

// Point-to-point release/acquire flags (64B-strided lines, zeroed per launch).
__device__ __forceinline__ void flag_set(unsigned* f) {
  __builtin_amdgcn_fence(__ATOMIC_RELEASE, "agent");
  __hip_atomic_store(f, 1u, __ATOMIC_RELAXED, __HIP_MEMORY_SCOPE_AGENT);
}
__device__ __forceinline__ void flag_wait(unsigned* f) {
  while (__hip_atomic_load(f, __ATOMIC_RELAXED, __HIP_MEMORY_SCOPE_AGENT) == 0u)
    __builtin_amdgcn_s_sleep(2);
}

// ---------------------------------------------------------------------------
// MFMA 3x3 SAME conv, co-tile split (R13's proven kernel, unchanged).
// ---------------------------------------------------------------------------
template<int COUT, int TILES, bool SE>
__global__ __launch_bounds__(256) void k_conv(
    const float* __restrict__ inA, const float* __restrict__ inB,
    const float* __restrict__ wA, const float* __restrict__ bA,
    const float* __restrict__ wB, const float* __restrict__ bB,
    float* __restrict__ outA, float* __restrict__ outB,
    int actA, int actB,
    const float* __restrict__ x,
    const float* __restrict__ sw1, const float* __restrict__ sb1,
    const float* __restrict__ sw2, const float* __restrict__ sb2,
    float* __restrict__ seo) {
  __shared__ unsigned short Xl[256 * 64];
  __shared__ unsigned short Wl[9 * 16 * 64];
  __shared__ float sp[64];
  __shared__ float sh1[32];
  const int b = blockIdx.x;
  const int t = threadIdx.x;

  if (SE && b >= 8 * TILES) {
    const int n = b - 8 * TILES;
    const int c = t >> 2, part = t & 3;
    const float* xp = x + (n * 64 + c) * 256 + part * 64;
    float s = 0.f;
    for (int k = 0; k < 64; ++k) s += xp[k];
    s += __shfl_xor(s, 1, 64);
    s += __shfl_xor(s, 2, 64);
    if (part == 0) sp[c] = s * (1.f / 256.f);
    __syncthreads();
    if (t < 32) {
      float a = sb1[t];
      for (int k = 0; k < 64; ++k) a += sw1[t * 64 + k] * sp[k];
      sh1[t] = a > 0.f ? a : 0.01f * a;
    }
    __syncthreads();
    if (t < 16) {
      float a = sb2[t];
      for (int k = 0; k < 32; ++k) a += sw2[t * 32 + k] * sh1[k];
      seo[n * 16 + t] = 1.f / (1.f + __expf(-a));
    }
    return;
  }

  const int n = b & 3;
  const int q = b >> 2;
  const int br = (q >= TILES) ? 1 : 0;
  const int ct = q - br * TILES;
  const int co0 = ct * 16;
  const float* inp = (br ? inB : inA) + n * 64 * 256;
  const float* wsrc = br ? wB : wA;
  const float* bias = br ? bB : bA;
  float* outp = (br ? outB : outA) + n * COUT * 256;
  const int act = br ? actB : actA;

  {
    const int p = t;
    #pragma unroll
    for (int q8 = 0; q8 < 8; ++q8) {
      vs8 v;
      #pragma unroll
      for (int j = 0; j < 8; ++j) v[j] = (short)f2bf(inp[(8 * q8 + j) * 256 + p]);
      *(vs8*)&Xl[p * 64 + ((q8 ^ (p & 7)) << 3)] = v;
    }
  }
  {
    const int col = t >> 4;
    const int sub = t & 15;
    const int co = co0 + col;
    if (co < COUT) {
      const float* wp = wsrc + (co * 64 + sub * 4) * 9;
      #pragma unroll
      for (int cc = 0; cc < 4; ++cc) {
        const int ci = sub * 4 + cc;
        #pragma unroll
        for (int e = 0; e < 9; ++e)
          Wl[(e * 16 + col) * 64 + (ci ^ ((col & 7) << 3))] = f2bf(wp[cc * 9 + e]);
      }
    } else {
      #pragma unroll
      for (int cc = 0; cc < 4; ++cc) {
        const int ci = sub * 4 + cc;
        #pragma unroll
        for (int e = 0; e < 9; ++e)
          Wl[(e * 16 + col) * 64 + (ci ^ ((col & 7) << 3))] = 0;
      }
    }
  }
  __syncthreads();

  const int w = t >> 6, lane = t & 63;
  const int px = lane & 15, kg = lane >> 4;
  vf4 acc[4];
  #pragma unroll
  for (int mt = 0; mt < 4; ++mt) acc[mt] = (vf4)0.f;

  for (int e = 0; e < 9; ++e) {
    const int dy = e / 3 - 1, dx = e % 3 - 1;
    const bool xok = (dx == 0) || (dx < 0 ? (px > 0) : (px < 15));
    const int xoff = xok ? dx : 0;
    #pragma unroll
    for (int ks = 0; ks < 2; ++ks) {
      vs8 bf = *(const vs8*)&Wl[(e * 16 + px) * 64 + (((ks * 4 + kg) ^ (px & 7)) << 3)];
      #pragma unroll
      for (int mt = 0; mt < 4; ++mt) {
        const int yy = 4 * w + mt + dy;
        if (yy < 0 || yy > 15) continue;
        const int ps = yy * 16 + px + xoff;
        vs8 a = *(const vs8*)&Xl[ps * 64 + (((ks * 4 + kg) ^ (ps & 7)) << 3)];
        if (!xok) a = (vs8)(short)0;
        acc[mt] = __builtin_amdgcn_mfma_f32_16x16x32_bf16(a, bf, acc[mt], 0, 0, 0);
      }
    }
  }

  const int co = co0 + px;
  if (co < COUT) {
    const float bv = bias[co];
    #pragma unroll
    for (int mt = 0; mt < 4; ++mt) {
      const int y = 4 * w + mt;
      vf4 v = acc[mt];
      #pragma unroll
      for (int j = 0; j < 4; ++j) {
        float s = v[j] + bv;
        if (act == 1) s = s > 0.f ? s : 0.01f * s;
        else if (act == 2) s = 1.f / (1.f + __expf(-s));
        v[j] = s;
      }
      *(vf4*)&outp[co * 256 + y * 16 + kg * 4] = v;
    }
  }
}

// ---------------------------------------------------------------------------
// Wave-local Chebyshev(NCHEB=16)-PCG, DPP SpMV (R13's verified math; only
// NCHEB changed 8->16: same stable recurrence, fewer outer iterations for
// the same total SpMV budget).
// ---------------------------------------------------------------------------
__device__ void pcg_unit(
    int unit, const float* __restrict__ att, const float* __restrict__ grad,
    float* __restrict__ sol, int maxit, float tol2) {
  const int sys = unit >> 1;
  const int wv = unit & 1;
  const int l = threadIdx.x & 63;
  const int row = l & 15;
  const int c4 = l >> 4;
  const int i0 = 16 * row + 4 * c4;

  const int n = sys >> 2, g = sys & 3;
  const float* ab = att + (n * 40 + g * 10) * 256;
  const float* gb = grad + (n * 40 + g * 10) * 256;

  int era, eda, erb, edb, ec, fa, fb;
  if (wv == 0) { fa = 0; fb = 2; era = 4; eda = 9; erb = 2; edb = 7; ec = 0; }
  else         { fa = 1; fb = 3; era = 8; eda = 5; erb = 6; edb = 3; ec = 1; }

  auto L4 = [](const float* p) { return *reinterpret_cast<const float4*>(p); };
  auto unp = [](float4 v, float* o) { o[0] = v.x; o[1] = v.y; o[2] = v.z; o[3] = v.w; };

  float wLa[4], wRa[4], wUa[4], wDa[4], wXa[4], dga[4], iva[4], rsa[4];
  float wLb[4], wRb[4], wUb[4], wDb[4], wXb[4], dgb[4], ivb[4], rsb[4];

  float rA[4], gA[4], dA[4], hA[4], uA[4] = {0,0,0,0}, vA[4] = {0,0,0,0};
  unp(L4(ab + era * 256 + i0), rA); unp(L4(gb + era * 256 + i0), gA);
  unp(L4(ab + eda * 256 + i0), dA); unp(L4(gb + eda * 256 + i0), hA);
  if (row > 0) { unp(L4(ab + eda * 256 + i0 - 16), uA); unp(L4(gb + eda * 256 + i0 - 16), vA); }
  float rlA = (l > 0) ? ab[era * 256 + i0 - 1] : 0.f;
  float glA = (l > 0) ? gb[era * 256 + i0 - 1] : 0.f;
  float cX[4], gX[4], cU[4] = {0,0,0,0}, gU[4] = {0,0,0,0};
  unp(L4(ab + ec * 256 + i0), cX); unp(L4(gb + ec * 256 + i0), gX);
  float clX = 0.f, glX = 0.f;
  if (wv == 0) { if (l > 0) { clX = ab[ec * 256 + i0 - 1]; glX = gb[ec * 256 + i0 - 1]; } }
  else if (row > 0) { unp(L4(ab + ec * 256 + i0 - 16), cU); unp(L4(gb + ec * 256 + i0 - 16), gU); }

  #pragma unroll
  for (int k = 0; k < 4; ++k) {
    wRa[k] = (k < 3 || c4 < 3) ? rA[k] * rA[k] : 0.f;
    wLa[k] = (k > 0) ? rA[k-1] * rA[k-1] : ((c4 > 0) ? rlA * rlA : 0.f);
    wDa[k] = (row < 15) ? dA[k] * dA[k] : 0.f;
    wUa[k] = (row > 0) ? uA[k] * uA[k] : 0.f;
    float rhs = wRa[k] * gA[k] - wLa[k] * ((k > 0) ? gA[k-1] : glA)
              + wDa[k] * hA[k] - wUa[k] * vA[k];
    float wx, gx;
    if (wv == 0) {
      wx = (k > 0) ? cX[k-1] * cX[k-1] : ((c4 > 0) ? clX * clX : 0.f);
      gx = (k > 0) ? gX[k-1] : glX;
    } else {
      wx = (row > 0) ? cU[k] * cU[k] : 0.f;
      gx = gU[k];
    }
    wXa[k] = wx;
    rhs -= wx * gx;
    rsa[k] = rhs;
    dga[k] = 1e-12f + wRa[k] + wLa[k] + wDa[k] + wUa[k] + wx;
  }

  float rB[4], gB[4], dB[4], hB[4], uB[4] = {0,0,0,0}, vB[4] = {0,0,0,0};
  unp(L4(ab + erb * 256 + i0), rB); unp(L4(gb + erb * 256 + i0), gB);
  unp(L4(ab + edb * 256 + i0), dB); unp(L4(gb + edb * 256 + i0), hB);
  if (row > 0) { unp(L4(ab + edb * 256 + i0 - 16), uB); unp(L4(gb + edb * 256 + i0 - 16), vB); }
  float rlB = (l > 0) ? ab[erb * 256 + i0 - 1] : 0.f;
  float glB = (l > 0) ? gb[erb * 256 + i0 - 1] : 0.f;

  #pragma unroll
  for (int k = 0; k < 4; ++k) {
    wRb[k] = (k < 3 || c4 < 3) ? rB[k] * rB[k] : 0.f;
    wLb[k] = (k > 0) ? rB[k-1] * rB[k-1] : ((c4 > 0) ? rlB * rlB : 0.f);
    wDb[k] = (row < 15) ? dB[k] * dB[k] : 0.f;
    wUb[k] = (row > 0) ? uB[k] * uB[k] : 0.f;
    float wx;
    if (wv == 0) wx = (k < 3 || c4 < 3) ? cX[k] * cX[k] : 0.f;
    else         wx = (row < 15) ? cX[k] * cX[k] : 0.f;
    wXb[k] = wx;
    rsb[k] = wRb[k] * gB[k] - wLb[k] * ((k > 0) ? gB[k-1] : glB)
           + wDb[k] * hB[k] - wUb[k] * vB[k]
           + wx * gX[k];
    dgb[k] = 1e-12f + wRb[k] + wLb[k] + wDb[k] + wUb[k] + wx;
  }

  if (l == 63) {
    float wr = rA[3] * rA[3], wd = dA[3] * dA[3];
    dga[3] += wr + wd;
    rsa[3] += wr * gA[3] + wd * hA[3];
    float wc = cX[3] * cX[3], wrb = rB[3] * rB[3], wdb = dB[3] * dB[3];
    dgb[3] += wc + wrb + wdb;
    rsb[3] += wc * gX[3] + wrb * gB[3] + wdb * hB[3];
  }
  #pragma unroll
  for (int k = 0; k < 4; ++k) { iva[k] = 1.f / dga[k]; ivb[k] = 1.f / dgb[k]; }

  float ua[4], ub[4], wa[4], wb[4];

  auto spmv = [&](const float (&ia_)[4], const float (&ib_)[4],
                  float (&oa)[4], float (&ob)[4]) {
    float aL = __shfl_up(ia_[3], 16, 64);
    float aR = __shfl_down(ia_[0], 16, 64);
    float bL = __shfl_up(ib_[3], 16, 64);
    float bR = __shfl_down(ib_[0], 16, 64);
    float aU[4], aD[4], bU[4], bD[4];
    #pragma unroll
    for (int k = 0; k < 4; ++k) {
      aU[k] = dppf<0x138>(ia_[k]);
      aD[k] = dppf<0x130>(ia_[k]);
      bU[k] = dppf<0x138>(ib_[k]);
      bD[k] = dppf<0x130>(ib_[k]);
    }
    float uaL[4] = {aL, ia_[0], ia_[1], ia_[2]};
    float uaR[4] = {ia_[1], ia_[2], ia_[3], aR};
    float ubL[4] = {bL, ib_[0], ib_[1], ib_[2]};
    float ubR[4] = {ib_[1], ib_[2], ib_[3], bR};
    #pragma unroll
    for (int k = 0; k < 4; ++k) {
      float cA = (wv == 0) ? ubL[k] : bU[k];
      float cB = (wv == 0) ? uaR[k] : aD[k];
      oa[k] = dga[k] * ia_[k] - wLa[k] * uaL[k] - wRa[k] * uaR[k]
            - wUa[k] * aU[k] - wDa[k] * aD[k] - wXa[k] * cA;
      ob[k] = dgb[k] * ib_[k] - wLb[k] * ubL[k] - wRb[k] * ubR[k]
            - wUb[k] * bU[k] - wDb[k] * bD[k] - wXb[k] * cB;
    }
  };

  constexpr float lo = 0.01f, hi = 2.0f;
  constexpr float th = (hi + lo) * 0.5f, dl = (hi - lo) * 0.5f, s1 = th / dl;

  float xa[4] = {0,0,0,0}, xb[4] = {0,0,0,0};
  float ra_[4], rb_[4], pa[4] = {0,0,0,0}, pb_[4] = {0,0,0,0};
  float sa[4] = {0,0,0,0}, sb[4] = {0,0,0,0};
  #pragma unroll
  for (int k = 0; k < 4; ++k) { ra_[k] = rsa[k]; rb_[k] = rsb[k]; }

  auto cheb = [&]() {
    float da_[4], db_[4], ta[4], tb[4], qa[4], qb[4];
    #pragma unroll
    for (int k = 0; k < 4; ++k) {
      da_[k] = (1.0f / th) * iva[k] * ra_[k];
      db_[k] = (1.0f / th) * ivb[k] * rb_[k];
      ua[k] = da_[k]; ub[k] = db_[k];
    }
    spmv(da_, db_, ta, tb);
    #pragma unroll
    for (int k = 0; k < 4; ++k) {
      wa[k] = ta[k]; wb[k] = tb[k];
      qa[k] = ra_[k] - ta[k]; qb[k] = rb_[k] - tb[k];
    }
    float rho = 1.0f / s1;
    #pragma unroll
    for (int j = 1; j < NCHEB; ++j) {
      float rho2 = 1.0f / (2.0f * s1 - rho);
      float c1 = rho2 * rho, c2 = 2.0f * rho2 / dl;
      #pragma unroll
      for (int k = 0; k < 4; ++k) {
        da_[k] = c1 * da_[k] + c2 * iva[k] * qa[k];
        db_[k] = c1 * db_[k] + c2 * ivb[k] * qb[k];
        ua[k] += da_[k]; ub[k] += db_[k];
      }
      spmv(da_, db_, ta, tb);
      #pragma unroll
      for (int k = 0; k < 4; ++k) {
        wa[k] += ta[k]; wb[k] += tb[k];
        qa[k] -= ta[k]; qb[k] -= tb[k];
      }
      rho = rho2;
    }
  };

  float gamma, delta;
  auto dots = [&]() {
    float gp = 0.f, dp = 0.f;
    #pragma unroll
    for (int k = 0; k < 4; ++k) {
      gp += ra_[k] * ua[k] + rb_[k] * ub[k];
      dp += wa[k] * ua[k] + wb[k] * ub[k];
    }
    gp += dppf<0xB1>(gp);            dp += dppf<0xB1>(dp);
    gp += dppf<0x4E>(gp);            dp += dppf<0x4E>(dp);
    gp += __shfl_xor(gp, 4, 64);     dp += __shfl_xor(dp, 4, 64);
    gp += dppf<0x128>(gp);           dp += dppf<0x128>(dp);
    gp += __shfl_xor(gp, 16, 64);    dp += __shfl_xor(dp, 16, 64);
    gp += __shfl_xor(gp, 32, 64);    dp += __shfl_xor(dp, 32, 64);
    gamma = gp; delta = dp;
  };

  cheb();
  dots();
  const float thresh = tol2 * gamma;
  float gamma_old = gamma, alpha_old = 1.f;

  for (int it = 0; it < maxit && gamma > thresh; ++it) {
    float beta = (it == 0) ? 0.f : gamma / gamma_old;
    float alpha = (it == 0) ? gamma / delta
                            : gamma / (delta - beta * gamma / alpha_old);
    #pragma unroll
    for (int k = 0; k < 4; ++k) {
      pa[k] = ua[k] + beta * pa[k];   pb_[k] = ub[k] + beta * pb_[k];
      sa[k] = wa[k] + beta * sa[k];   sb[k] = wb[k] + beta * sb[k];
      xa[k] += alpha * pa[k];         xb[k] += alpha * pb_[k];
      ra_[k] -= alpha * sa[k];        rb_[k] -= alpha * sb[k];
    }
    gamma_old = gamma; alpha_old = alpha;
    cheb();
    dots();
  }

  float4* sol4 = reinterpret_cast<float4*>(sol);
  const int slot = 4 * row + c4;
  sol4[sys * 256 + fa * 64 + slot] = make_float4(xa[0], xa[1], xa[2], xa[3]);
  sol4[sys * 256 + fb * 64 + slot] = make_float4(xb[0], xb[1], xb[2], xb[3]);
}

// ---------------------------------------------------------------------------
// k_solve (R14's verified kernel): 32 blocks x 512 thr. Wave 0 = pcg unit.
// Non-leaders flag sol and exit; leaders (bid%8==0) pre-stage post weights on
// waves 1-7 during pcg, join sibling flags, then run GN + SE + post conv.
// ---------------------------------------------------------------------------
__global__ __launch_bounds__(512, 1) void k_solve(
    const float* __restrict__ att, const float* __restrict__ grad,
    const float* __restrict__ se,
    const float* __restrict__ gn_w, const float* __restrict__ gn_b,
    const float* __restrict__ pw, const float* __restrict__ pb,
    float* __restrict__ sol, float* __restrict__ out,
    unsigned* __restrict__ flags, int maxit, float tol2) {
  __shared__ unsigned short Hl[256 * 24];
  __shared__ unsigned short Wp[9 * 128 * 24];
  __shared__ float rs[8], rs2[8];
  const int bid = blockIdx.x;
  const int t = threadIdx.x;
  const bool leader = (bid & 7) == 0;

  if (t < 64) {
    pcg_unit(bid, att, grad, sol, maxit, tol2);   // wave 0
    if (t == 0 && !leader) flag_set(flags + bid * 16);
  } else if (leader) {
    for (int i = t - 64; i < 128 * 16 * 9; i += 448) {
      const int co = i / 144;
      const int rem = i - co * 144;
      const int ci = rem / 9;
      const int e = rem - ci * 9;
      Wp[(e * 128 + co) * 24 + ci] = f2bf(pw[i]);
    }
  }
  if (!leader) return;

  if (t == 0) {
    #pragma unroll
    for (int u = 1; u < 8; ++u) flag_wait(flags + (bid + u) * 16);
    __builtin_amdgcn_fence(__ATOMIC_ACQUIRE, "agent");
  }
  __syncthreads();

  const int n = bid >> 3;
  const int w = t >> 6, lane = t & 63;

  float v[8];
  {
    const vf4* s4 = (const vf4*)(sol + n * 4096 + 8 * t);
    vf4 a = s4[0], b = s4[1];
    v[0]=a[0];v[1]=a[1];v[2]=a[2];v[3]=a[3];v[4]=b[0];v[5]=b[1];v[6]=b[2];v[7]=b[3];
  }
  float s = 0.f, s2 = 0.f;
  #pragma unroll
  for (int k = 0; k < 8; ++k) { s += v[k]; s2 += v[k] * v[k]; }
  #pragma unroll
  for (int o = 1; o <= 32; o <<= 1) { s += __shfl_xor(s, o, 64); s2 += __shfl_xor(s2, o, 64); }
  if (lane == 0) { rs[w] = s; rs2[w] = s2; }
  __syncthreads();
  float sm = 0.f, sq = 0.f;
  #pragma unroll
  for (int k = 0; k < 8; ++k) { sm += rs[k]; sq += rs2[k]; }
  const float mu = sm * (1.f / 4096.f);
  const float rstd = rsqrtf(sq * (1.f / 4096.f) - mu * mu + 1e-5f);

  const int c = t >> 5;
  const int p0 = (8 * t) & 255;
  const float sev = se[n * 16 + c];
  const float sc = rstd * gn_w[c] * sev;
  const float of = (gn_b[c] - mu * rstd * gn_w[c]) * sev;
  #pragma unroll
  for (int k = 0; k < 8; ++k) Hl[(p0 + k) * 24 + c] = f2bf(v[k] * sc + of);
  __syncthreads();

  const int cl = lane & 31, h = lane >> 5;
  const int px = cl & 15, y0 = 2 * w + (cl >> 4);
  vf16 acc[4];
  #pragma unroll
  for (int nt = 0; nt < 4; ++nt) acc[nt] = (vf16)0.f;
  for (int e = 0; e < 9; ++e) {
    const int dy = e / 3 - 1, dx = e % 3 - 1;
    const int yy = y0 + dy, xx = px + dx;
    const bool ok = (yy >= 0 && yy < 16 && xx >= 0 && xx < 16);
    const int ps = ok ? yy * 16 + xx : 0;
    vs8 a = *(const vs8*)&Hl[ps * 24 + h * 8];
    if (!ok) a = (vs8)(short)0;
    #pragma unroll
    for (int nt = 0; nt < 4; ++nt) {
      vs8 bf = *(const vs8*)&Wp[(e * 128 + nt * 32 + cl) * 24 + h * 8];
      acc[nt] = __builtin_amdgcn_mfma_f32_32x32x16_bf16(a, bf, acc[nt], 0, 0, 0);
    }
  }
  float* op = out + n * 32768;
  #pragma unroll
  for (int nt = 0; nt < 4; ++nt) {
    const int co = nt * 32 + cl;
    const float bv = pb[co];
    #pragma unroll
    for (int rq = 0; rq < 4; ++rq) {
      vf4 vv;
      #pragma unroll
      for (int j = 0; j < 4; ++j) vv[j] = acc[nt][rq * 4 + j] + bv;
      *(vf4*)&op[co * 256 + 32 * w + 8 * rq + 4 * h] = vv;
    }
  }
}

extern "C" void kernel_launch(void* const* d_in, const int* in_sizes, int n_in,
                              void* d_out, int out_size, void* d_ws, size_t ws_size,
                              hipStream_t stream) {
  const float* x       = (const float*)d_in[0];
  const float* grad_w1 = (const float*)d_in[1];
  const float* grad_b1 = (const float*)d_in[2];
  const float* grad_w2 = (const float*)d_in[3];
  const float* grad_b2 = (const float*)d_in[4];
  const float* att_w1  = (const float*)d_in[5];
  const float* att_b1  = (const float*)d_in[6];
  const float* att_w2  = (const float*)d_in[7];
  const float* att_b2  = (const float*)d_in[8];
  const float* se_w1   = (const float*)d_in[9];
  const float* se_b1   = (const float*)d_in[10];
  const float* se_w2   = (const float*)d_in[11];
  const float* se_b2   = (const float*)d_in[12];
  const float* gn_w    = (const float*)d_in[13];
  const float* gn_b    = (const float*)d_in[14];
  const float* post_w  = (const float*)d_in[15];
  const float* post_b  = (const float*)d_in[16];
  float* out = (float*)d_out;
  float* ws = (float*)d_ws;

  float* t1    = ws;                // 65536 (grad conv1 out)
  float* t2    = ws + 65536;        // 65536 (att conv1 out)
  float* gradb = ws + 131072;       // 40960
  float* attb  = ws + 172032;       // 40960
  float* seb   = ws + 212992;       // 64
  float* solb  = ws + 213056;       // 16384
  unsigned* flags = (unsigned*)(ws + 230000); // 32 x 64B = 2 KB

  hipMemsetAsync(flags, 0, 2048, stream);
  // conv1: 2 branches x 4 images x 4 co-tiles = 32 blocks + 4 SE blocks
  k_conv<64, 4, true><<<36, 256, 0, stream>>>(
      x, x, grad_w1, grad_b1, att_w1, att_b1, t1, t2, 1, 1,
      x, se_w1, se_b1, se_w2, se_b2, seb);
  // conv2: 2 x 4 x 3 co-tiles = 24 blocks
  k_conv<40, 3, false><<<24, 256, 0, stream>>>(
      t1, t2, grad_w2, grad_b2, att_w2, att_b2, gradb, attb, 0, 2,
      nullptr, nullptr, nullptr, nullptr, nullptr, nullptr);
  // solve: pcg (NCHEB=16, fewer outers) + GN + SE + post conv, one dispatch
  k_solve<<<32, 512, 0, stream>>>(
      attb, gradb, seb, gn_w, gn_b, post_w, post_b,
      solb, out, flags, 40, 3e-6f);
}

// Round 20
// 87.204 us; speedup vs baseline: 1.4337x; 1.1228x over previous
//
#include <hip/hip_runtime.h>

#define NCHEB 8

typedef __attribute__((ext_vector_type(8))) short vs8;
typedef __attribute__((ext_vector_type(4))) float vf4;
typedef __attribute__((ext_vector_type(16))) float vf16;

__device__ __forceinline__ unsigned short f2bf(float f) {
  union { float f; unsigned int u; } x; x.f = f;
  unsigned int r = (x.u + 0x7FFFu + ((x.u >> 16) & 1u)) >> 16;
  return (unsigned short)r;
}

// DPP move: 0x138 = wave_shr:1, 0x130 = wave_shl:1, 0xB1 = quad_perm xor1,
// 0x4E = quad_perm xor2, 0x128 = row_ror:8 (xor8 within 16-lane rows).
template<int CTRL>
__device__ __forceinline__ float dppf(float x) {
  return __int_as_float(__builtin_amdgcn_mov_dpp(__float_as_int(x), CTRL, 0xF, 0xF, true));
}

// ---------------------------------------------------------------------------
// MFMA 3x3 SAME conv, co-tile split (R13's proven kernel, unchanged).
// ---------------------------------------------------------------------------
template<int COUT, int TILES, bool SE>
__global__ __launch_bounds__(256) void k_conv(
    const float* __restrict__ inA, const float* __restrict__ inB,
    const float* __restrict__ wA, const float* __restrict__ bA,
    const float* __restrict__ wB, const float* __restrict__ bB,
    float* __restrict__ outA, float* __restrict__ outB,
    int actA, int actB,
    const float* __restrict__ x,
    const float* __restrict__ sw1, const float* __restrict__ sb1,
    const float* __restrict__ sw2, const float* __restrict__ sb2,
    float* __restrict__ seo) {
  __shared__ unsigned short Xl[256 * 64];
  __shared__ unsigned short Wl[9 * 16 * 64];
  __shared__ float sp[64];
  __shared__ float sh1[32];
  const int b = blockIdx.x;
  const int t = threadIdx.x;

  if (SE && b >= 8 * TILES) {
    const int n = b - 8 * TILES;
    const int c = t >> 2, part = t & 3;
    const float* xp = x + (n * 64 + c) * 256 + part * 64;
    float s = 0.f;
    for (int k = 0; k < 64; ++k) s += xp[k];
    s += __shfl_xor(s, 1, 64);
    s += __shfl_xor(s, 2, 64);
    if (part == 0) sp[c] = s * (1.f / 256.f);
    __syncthreads();
    if (t < 32) {
      float a = sb1[t];
      for (int k = 0; k < 64; ++k) a += sw1[t * 64 + k] * sp[k];
      sh1[t] = a > 0.f ? a : 0.01f * a;
    }
    __syncthreads();
    if (t < 16) {
      float a = sb2[t];
      for (int k = 0; k < 32; ++k) a += sw2[t * 32 + k] * sh1[k];
      seo[n * 16 + t] = 1.f / (1.f + __expf(-a));
    }
    return;
  }

  const int n = b & 3;
  const int q = b >> 2;
  const int br = (q >= TILES) ? 1 : 0;
  const int ct = q - br * TILES;
  const int co0 = ct * 16;
  const float* inp = (br ? inB : inA) + n * 64 * 256;
  const float* wsrc = br ? wB : wA;
  const float* bias = br ? bB : bA;
  float* outp = (br ? outB : outA) + n * COUT * 256;
  const int act = br ? actB : actA;

  {
    const int p = t;
    #pragma unroll
    for (int q8 = 0; q8 < 8; ++q8) {
      vs8 v;
      #pragma unroll
      for (int j = 0; j < 8; ++j) v[j] = (short)f2bf(inp[(8 * q8 + j) * 256 + p]);
      *(vs8*)&Xl[p * 64 + ((q8 ^ (p & 7)) << 3)] = v;
    }
  }
  {
    const int col = t >> 4;
    const int sub = t & 15;
    const int co = co0 + col;
    if (co < COUT) {
      const float* wp = wsrc + (co * 64 + sub * 4) * 9;
      #pragma unroll
      for (int cc = 0; cc < 4; ++cc) {
        const int ci = sub * 4 + cc;
        #pragma unroll
        for (int e = 0; e < 9; ++e)
          Wl[(e * 16 + col) * 64 + (ci ^ ((col & 7) << 3))] = f2bf(wp[cc * 9 + e]);
      }
    } else {
      #pragma unroll
      for (int cc = 0; cc < 4; ++cc) {
        const int ci = sub * 4 + cc;
        #pragma unroll
        for (int e = 0; e < 9; ++e)
          Wl[(e * 16 + col) * 64 + (ci ^ ((col & 7) << 3))] = 0;
      }
    }
  }
  __syncthreads();

  const int w = t >> 6, lane = t & 63;
  const int px = lane & 15, kg = lane >> 4;
  vf4 acc[4];
  #pragma unroll
  for (int mt = 0; mt < 4; ++mt) acc[mt] = (vf4)0.f;

  for (int e = 0; e < 9; ++e) {
    const int dy = e / 3 - 1, dx = e % 3 - 1;
    const bool xok = (dx == 0) || (dx < 0 ? (px > 0) : (px < 15));
    const int xoff = xok ? dx : 0;
    #pragma unroll
    for (int ks = 0; ks < 2; ++ks) {
      vs8 bf = *(const vs8*)&Wl[(e * 16 + px) * 64 + (((ks * 4 + kg) ^ (px & 7)) << 3)];
      #pragma unroll
      for (int mt = 0; mt < 4; ++mt) {
        const int yy = 4 * w + mt + dy;
        if (yy < 0 || yy > 15) continue;
        const int ps = yy * 16 + px + xoff;
        vs8 a = *(const vs8*)&Xl[ps * 64 + (((ks * 4 + kg) ^ (ps & 7)) << 3)];
        if (!xok) a = (vs8)(short)0;
        acc[mt] = __builtin_amdgcn_mfma_f32_16x16x32_bf16(a, bf, acc[mt], 0, 0, 0);
      }
    }
  }

  const int co = co0 + px;
  if (co < COUT) {
    const float bv = bias[co];
    #pragma unroll
    for (int mt = 0; mt < 4; ++mt) {
      const int y = 4 * w + mt;
      vf4 v = acc[mt];
      #pragma unroll
      for (int j = 0; j < 4; ++j) {
        float s = v[j] + bv;
        if (act == 1) s = s > 0.f ? s : 0.01f * s;
        else if (act == 2) s = 1.f / (1.f + __expf(-s));
        v[j] = s;
      }
      *(vf4*)&outp[co * 256 + y * 16 + kg * 4] = v;
    }
  }
}

// ---------------------------------------------------------------------------
// Wave-local Chebyshev(NCHEB=8)-PCG, DPP SpMV (R13's verified math, verbatim).
// ---------------------------------------------------------------------------
__device__ void pcg_unit(
    int unit, const float* __restrict__ att, const float* __restrict__ grad,
    float* __restrict__ sol, int maxit, float tol2) {
  const int sys = unit >> 1;
  const int wv = unit & 1;
  const int l = threadIdx.x & 63;
  const int row = l & 15;
  const int c4 = l >> 4;
  const int i0 = 16 * row + 4 * c4;

  const int n = sys >> 2, g = sys & 3;
  const float* ab = att + (n * 40 + g * 10) * 256;
  const float* gb = grad + (n * 40 + g * 10) * 256;

  int era, eda, erb, edb, ec, fa, fb;
  if (wv == 0) { fa = 0; fb = 2; era = 4; eda = 9; erb = 2; edb = 7; ec = 0; }
  else         { fa = 1; fb = 3; era = 8; eda = 5; erb = 6; edb = 3; ec = 1; }

  auto L4 = [](const float* p) { return *reinterpret_cast<const float4*>(p); };
  auto unp = [](float4 v, float* o) { o[0] = v.x; o[1] = v.y; o[2] = v.z; o[3] = v.w; };

  float wLa[4], wRa[4], wUa[4], wDa[4], wXa[4], dga[4], iva[4], rsa[4];
  float wLb[4], wRb[4], wUb[4], wDb[4], wXb[4], dgb[4], ivb[4], rsb[4];

  float rA[4], gA[4], dA[4], hA[4], uA[4] = {0,0,0,0}, vA[4] = {0,0,0,0};
  unp(L4(ab + era * 256 + i0), rA); unp(L4(gb + era * 256 + i0), gA);
  unp(L4(ab + eda * 256 + i0), dA); unp(L4(gb + eda * 256 + i0), hA);
  if (row > 0) { unp(L4(ab + eda * 256 + i0 - 16), uA); unp(L4(gb + eda * 256 + i0 - 16), vA); }
  float rlA = (l > 0) ? ab[era * 256 + i0 - 1] : 0.f;
  float glA = (l > 0) ? gb[era * 256 + i0 - 1] : 0.f;
  float cX[4], gX[4], cU[4] = {0,0,0,0}, gU[4] = {0,0,0,0};
  unp(L4(ab + ec * 256 + i0), cX); unp(L4(gb + ec * 256 + i0), gX);
  float clX = 0.f, glX = 0.f;
  if (wv == 0) { if (l > 0) { clX = ab[ec * 256 + i0 - 1]; glX = gb[ec * 256 + i0 - 1]; } }
  else if (row > 0) { unp(L4(ab + ec * 256 + i0 - 16), cU); unp(L4(gb + ec * 256 + i0 - 16), gU); }

  #pragma unroll
  for (int k = 0; k < 4; ++k) {
    wRa[k] = (k < 3 || c4 < 3) ? rA[k] * rA[k] : 0.f;
    wLa[k] = (k > 0) ? rA[k-1] * rA[k-1] : ((c4 > 0) ? rlA * rlA : 0.f);
    wDa[k] = (row < 15) ? dA[k] * dA[k] : 0.f;
    wUa[k] = (row > 0) ? uA[k] * uA[k] : 0.f;
    float rhs = wRa[k] * gA[k] - wLa[k] * ((k > 0) ? gA[k-1] : glA)
              + wDa[k] * hA[k] - wUa[k] * vA[k];
    float wx, gx;
    if (wv == 0) {
      wx = (k > 0) ? cX[k-1] * cX[k-1] : ((c4 > 0) ? clX * clX : 0.f);
      gx = (k > 0) ? gX[k-1] : glX;
    } else {
      wx = (row > 0) ? cU[k] * cU[k] : 0.f;
      gx = gU[k];
    }
    wXa[k] = wx;
    rhs -= wx * gx;
    rsa[k] = rhs;
    dga[k] = 1e-12f + wRa[k] + wLa[k] + wDa[k] + wUa[k] + wx;
  }

  float rB[4], gB[4], dB[4], hB[4], uB[4] = {0,0,0,0}, vB[4] = {0,0,0,0};
  unp(L4(ab + erb * 256 + i0), rB); unp(L4(gb + erb * 256 + i0), gB);
  unp(L4(ab + edb * 256 + i0), dB); unp(L4(gb + edb * 256 + i0), hB);
  if (row > 0) { unp(L4(ab + edb * 256 + i0 - 16), uB); unp(L4(gb + edb * 256 + i0 - 16), vB); }
  float rlB = (l > 0) ? ab[erb * 256 + i0 - 1] : 0.f;
  float glB = (l > 0) ? gb[erb * 256 + i0 - 1] : 0.f;

  #pragma unroll
  for (int k = 0; k < 4; ++k) {
    wRb[k] = (k < 3 || c4 < 3) ? rB[k] * rB[k] : 0.f;
    wLb[k] = (k > 0) ? rB[k-1] * rB[k-1] : ((c4 > 0) ? rlB * rlB : 0.f);
    wDb[k] = (row < 15) ? dB[k] * dB[k] : 0.f;
    wUb[k] = (row > 0) ? uB[k] * uB[k] : 0.f;
    float wx;
    if (wv == 0) wx = (k < 3 || c4 < 3) ? cX[k] * cX[k] : 0.f;
    else         wx = (row < 15) ? cX[k] * cX[k] : 0.f;
    wXb[k] = wx;
    rsb[k] = wRb[k] * gB[k] - wLb[k] * ((k > 0) ? gB[k-1] : glB)
           + wDb[k] * hB[k] - wUb[k] * vB[k]
           + wx * gX[k];
    dgb[k] = 1e-12f + wRb[k] + wLb[k] + wDb[k] + wUb[k] + wx;
  }

  if (l == 63) {
    float wr = rA[3] * rA[3], wd = dA[3] * dA[3];
    dga[3] += wr + wd;
    rsa[3] += wr * gA[3] + wd * hA[3];
    float wc = cX[3] * cX[3], wrb = rB[3] * rB[3], wdb = dB[3] * dB[3];
    dgb[3] += wc + wrb + wdb;
    rsb[3] += wc * gX[3] + wrb * gB[3] + wdb * hB[3];
  }
  #pragma unroll
  for (int k = 0; k < 4; ++k) { iva[k] = 1.f / dga[k]; ivb[k] = 1.f / dgb[k]; }

  float ua[4], ub[4], wa[4], wb[4];

  auto spmv = [&](const float (&ia_)[4], const float (&ib_)[4],
                  float (&oa)[4], float (&ob)[4]) {
    float aL = __shfl_up(ia_[3], 16, 64);
    float aR = __shfl_down(ia_[0], 16, 64);
    float bL = __shfl_up(ib_[3], 16, 64);
    float bR = __shfl_down(ib_[0], 16, 64);
    float aU[4], aD[4], bU[4], bD[4];
    #pragma unroll
    for (int k = 0; k < 4; ++k) {
      aU[k] = dppf<0x138>(ia_[k]);
      aD[k] = dppf<0x130>(ia_[k]);
      bU[k] = dppf<0x138>(ib_[k]);
      bD[k] = dppf<0x130>(ib_[k]);
    }
    float uaL[4] = {aL, ia_[0], ia_[1], ia_[2]};
    float uaR[4] = {ia_[1], ia_[2], ia_[3], aR};
    float ubL[4] = {bL, ib_[0], ib_[1], ib_[2]};
    float ubR[4] = {ib_[1], ib_[2], ib_[3], bR};
    #pragma unroll
    for (int k = 0; k < 4; ++k) {
      float cA = (wv == 0) ? ubL[k] : bU[k];
      float cB = (wv == 0) ? uaR[k] : aD[k];
      oa[k] = dga[k] * ia_[k] - wLa[k] * uaL[k] - wRa[k] * uaR[k]
            - wUa[k] * aU[k] - wDa[k] * aD[k] - wXa[k] * cA;
      ob[k] = dgb[k] * ib_[k] - wLb[k] * ubL[k] - wRb[k] * ubR[k]
            - wUb[k] * bU[k] - wDb[k] * bD[k] - wXb[k] * cB;
    }
  };

  constexpr float lo = 0.01f, hi = 2.0f;
  constexpr float th = (hi + lo) * 0.5f, dl = (hi - lo) * 0.5f, s1 = th / dl;

  float xa[4] = {0,0,0,0}, xb[4] = {0,0,0,0};
  float ra_[4], rb_[4], pa[4] = {0,0,0,0}, pb_[4] = {0,0,0,0};
  float sa[4] = {0,0,0,0}, sb[4] = {0,0,0,0};
  #pragma unroll
  for (int k = 0; k < 4; ++k) { ra_[k] = rsa[k]; rb_[k] = rsb[k]; }

  auto cheb = [&]() {
    float da_[4], db_[4], ta[4], tb[4], qa[4], qb[4];
    #pragma unroll
    for (int k = 0; k < 4; ++k) {
      da_[k] = (1.0f / th) * iva[k] * ra_[k];
      db_[k] = (1.0f / th) * ivb[k] * rb_[k];
      ua[k] = da_[k]; ub[k] = db_[k];
    }
    spmv(da_, db_, ta, tb);
    #pragma unroll
    for (int k = 0; k < 4; ++k) {
      wa[k] = ta[k]; wb[k] = tb[k];
      qa[k] = ra_[k] - ta[k]; qb[k] = rb_[k] - tb[k];
    }
    float rho = 1.0f / s1;
    #pragma unroll
    for (int j = 1; j < NCHEB; ++j) {
      float rho2 = 1.0f / (2.0f * s1 - rho);
      float c1 = rho2 * rho, c2 = 2.0f * rho2 / dl;
      #pragma unroll
      for (int k = 0; k < 4; ++k) {
        da_[k] = c1 * da_[k] + c2 * iva[k] * qa[k];
        db_[k] = c1 * db_[k] + c2 * ivb[k] * qb[k];
        ua[k] += da_[k]; ub[k] += db_[k];
      }
      spmv(da_, db_, ta, tb);
      #pragma unroll
      for (int k = 0; k < 4; ++k) {
        wa[k] += ta[k]; wb[k] += tb[k];
        qa[k] -= ta[k]; qb[k] -= tb[k];
      }
      rho = rho2;
    }
  };

  float gamma, delta;
  auto dots = [&]() {
    float gp = 0.f, dp = 0.f;
    #pragma unroll
    for (int k = 0; k < 4; ++k) {
      gp += ra_[k] * ua[k] + rb_[k] * ub[k];
      dp += wa[k] * ua[k] + wb[k] * ub[k];
    }
    gp += dppf<0xB1>(gp);            dp += dppf<0xB1>(dp);
    gp += dppf<0x4E>(gp);            dp += dppf<0x4E>(dp);
    gp += __shfl_xor(gp, 4, 64);     dp += __shfl_xor(dp, 4, 64);
    gp += dppf<0x128>(gp);           dp += dppf<0x128>(dp);
    gp += __shfl_xor(gp, 16, 64);    dp += __shfl_xor(dp, 16, 64);
    gp += __shfl_xor(gp, 32, 64);    dp += __shfl_xor(dp, 32, 64);
    gamma = gp; delta = dp;
  };

  cheb();
  dots();
  const float thresh = tol2 * gamma;
  float gamma_old = gamma, alpha_old = 1.f;

  for (int it = 0; it < maxit && gamma > thresh; ++it) {
    float beta = (it == 0) ? 0.f : gamma / gamma_old;
    float alpha = (it == 0) ? gamma / delta
                            : gamma / (delta - beta * gamma / alpha_old);
    #pragma unroll
    for (int k = 0; k < 4; ++k) {
      pa[k] = ua[k] + beta * pa[k];   pb_[k] = ub[k] + beta * pb_[k];
      sa[k] = wa[k] + beta * sa[k];   sb[k] = wb[k] + beta * sb[k];
      xa[k] += alpha * pa[k];         xb[k] += alpha * pb_[k];
      ra_[k] -= alpha * sa[k];        rb_[k] -= alpha * sb[k];
    }
    gamma_old = gamma; alpha_old = alpha;
    cheb();
    dots();
  }

  float4* sol4 = reinterpret_cast<float4*>(sol);
  const int slot = 4 * row + c4;
  sol4[sys * 256 + fa * 64 + slot] = make_float4(xa[0], xa[1], xa[2], xa[3]);
  sol4[sys * 256 + fb * 64 + slot] = make_float4(xb[0], xb[1], xb[2], xb[3]);
}

// ---------------------------------------------------------------------------
// k_solve: 4 blocks x 512 threads. Wave w solves pcg unit 8*bid + w (all 8
// units of image bid => 8 waves/CU = 2 waves/SIMD, hiding the latency chain;
// DPP spmv keeps LDS traffic 5x below R9's saturated variant). Then a plain
// __syncthreads (no flags, same block) and the R13 post body for image bid.
// ---------------------------------------------------------------------------
__global__ __launch_bounds__(512, 1) void k_solve(
    const float* __restrict__ att, const float* __restrict__ grad,
    const float* __restrict__ se,
    const float* __restrict__ gn_w, const float* __restrict__ gn_b,
    const float* __restrict__ pw, const float* __restrict__ pb,
    float* __restrict__ sol, float* __restrict__ out,
    int maxit, float tol2) {
  __shared__ unsigned short Hl[256 * 24];
  __shared__ unsigned short Wp[9 * 128 * 24];
  __shared__ float rs[8], rs2[8];
  const int bid = blockIdx.x;
  const int t = threadIdx.x;

  pcg_unit(8 * bid + (t >> 6), att, grad, sol, maxit, tol2);
  __syncthreads();   // sol for image bid complete & visible block-wide

  const int n = bid;
  const int w = t >> 6, lane = t & 63;

  float v[8];
  {
    const vf4* s4 = (const vf4*)(sol + n * 4096 + 8 * t);
    vf4 a = s4[0], b = s4[1];
    v[0]=a[0];v[1]=a[1];v[2]=a[2];v[3]=a[3];v[4]=b[0];v[5]=b[1];v[6]=b[2];v[7]=b[3];
  }
  float s = 0.f, s2 = 0.f;
  #pragma unroll
  for (int k = 0; k < 8; ++k) { s += v[k]; s2 += v[k] * v[k]; }
  #pragma unroll
  for (int o = 1; o <= 32; o <<= 1) { s += __shfl_xor(s, o, 64); s2 += __shfl_xor(s2, o, 64); }
  if (lane == 0) { rs[w] = s; rs2[w] = s2; }

  {
    const int co = t >> 2, sub = t & 3;
    const float* wp0 = pw + (co * 16 + sub * 4) * 9;
    #pragma unroll
    for (int cc = 0; cc < 4; ++cc) {
      const int ci = sub * 4 + cc;
      #pragma unroll
      for (int e = 0; e < 9; ++e)
        Wp[(e * 128 + co) * 24 + ci] = f2bf(wp0[cc * 9 + e]);
    }
  }
  __syncthreads();
  float sm = 0.f, sq = 0.f;
  #pragma unroll
  for (int k = 0; k < 8; ++k) { sm += rs[k]; sq += rs2[k]; }
  const float mu = sm * (1.f / 4096.f);
  const float rstd = rsqrtf(sq * (1.f / 4096.f) - mu * mu + 1e-5f);

  const int c = t >> 5;
  const int p0 = (8 * t) & 255;
  const float sev = se[n * 16 + c];
  const float sc = rstd * gn_w[c] * sev;
  const float of = (gn_b[c] - mu * rstd * gn_w[c]) * sev;
  #pragma unroll
  for (int k = 0; k < 8; ++k) Hl[(p0 + k) * 24 + c] = f2bf(v[k] * sc + of);
  __syncthreads();

  const int cl = lane & 31, h = lane >> 5;
  const int px = cl & 15, y0 = 2 * w + (cl >> 4);
  vf16 acc[4];
  #pragma unroll
  for (int nt = 0; nt < 4; ++nt) acc[nt] = (vf16)0.f;
  for (int e = 0; e < 9; ++e) {
    const int dy = e / 3 - 1, dx = e % 3 - 1;
    const int yy = y0 + dy, xx = px + dx;
    const bool ok = (yy >= 0 && yy < 16 && xx >= 0 && xx < 16);
    const int ps = ok ? yy * 16 + xx : 0;
    vs8 a = *(const vs8*)&Hl[ps * 24 + h * 8];
    if (!ok) a = (vs8)(short)0;
    #pragma unroll
    for (int nt = 0; nt < 4; ++nt) {
      vs8 bf = *(const vs8*)&Wp[(e * 128 + nt * 32 + cl) * 24 + h * 8];
      acc[nt] = __builtin_amdgcn_mfma_f32_32x32x16_bf16(a, bf, acc[nt], 0, 0, 0);
    }
  }
  float* op = out + n * 32768;
  #pragma unroll
  for (int nt = 0; nt < 4; ++nt) {
    const int co = nt * 32 + cl;
    const float bv = pb[co];
    #pragma unroll
    for (int rq = 0; rq < 4; ++rq) {
      vf4 vv;
      #pragma unroll
      for (int j = 0; j < 4; ++j) vv[j] = acc[nt][rq * 4 + j] + bv;
      *(vf4*)&op[co * 256 + 32 * w + 8 * rq + 4 * h] = vv;
    }
  }
}

extern "C" void kernel_launch(void* const* d_in, const int* in_sizes, int n_in,
                              void* d_out, int out_size, void* d_ws, size_t ws_size,
                              hipStream_t stream) {
  const float* x       = (const float*)d_in[0];
  const float* grad_w1 = (const float*)d_in[1];
  const float* grad_b1 = (const float*)d_in[2];
  const float* grad_w2 = (const float*)d_in[3];
  const float* grad_b2 = (const float*)d_in[4];
  const float* att_w1  = (const float*)d_in[5];
  const float* att_b1  = (const float*)d_in[6];
  const float* att_w2  = (const float*)d_in[7];
  const float* att_b2  = (const float*)d_in[8];
  const float* se_w1   = (const float*)d_in[9];
  const float* se_b1   = (const float*)d_in[10];
  const float* se_w2   = (const float*)d_in[11];
  const float* se_b2   = (const float*)d_in[12];
  const float* gn_w    = (const float*)d_in[13];
  const float* gn_b    = (const float*)d_in[14];
  const float* post_w  = (const float*)d_in[15];
  const float* post_b  = (const float*)d_in[16];
  float* out = (float*)d_out;
  float* ws = (float*)d_ws;

  float* t1    = ws;                // 65536 (grad conv1 out)
  float* t2    = ws + 65536;        // 65536 (att conv1 out)
  float* gradb = ws + 131072;       // 40960
  float* attb  = ws + 172032;       // 40960
  float* seb   = ws + 212992;       // 64
  float* solb  = ws + 213056;       // 16384

  // conv1: 2 branches x 4 images x 4 co-tiles = 32 blocks + 4 SE blocks
  k_conv<64, 4, true><<<36, 256, 0, stream>>>(
      x, x, grad_w1, grad_b1, att_w1, att_b1, t1, t2, 1, 1,
      x, se_w1, se_b1, se_w2, se_b2, seb);
  // conv2: 2 x 4 x 3 co-tiles = 24 blocks
  k_conv<40, 3, false><<<24, 256, 0, stream>>>(
      t1, t2, grad_w2, grad_b2, att_w2, att_b2, gradb, attb, 0, 2,
      nullptr, nullptr, nullptr, nullptr, nullptr, nullptr);
  // solve: 4 blocks x 8 pcg waves (2/SIMD) + GN + SE + post, no flags
  k_solve<<<4, 512, 0, stream>>>(
      attb, gradb, seb, gn_w, gn_b, post_w, post_b,
      solb, out, 100, 3e-6f);
}

// Round 21
// 61.530 us; speedup vs baseline: 2.0320x; 1.4173x over previous
//
#include <hip/hip_runtime.h>

#define NCHEB 8

typedef __attribute__((ext_vector_type(8))) short vs8;
typedef __attribute__((ext_vector_type(4))) float vf4;
typedef __attribute__((ext_vector_type(16))) float vf16;

__device__ __forceinline__ unsigned short f2bf(float f) {
  union { float f; unsigned int u; } x; x.f = f;
  unsigned int r = (x.u + 0x7FFFu + ((x.u >> 16) & 1u)) >> 16;
  return (unsigned short)r;
}

// DPP move: 0x138 = wave_shr:1 (lane l <- l-1), 0x130 = wave_shl:1 (l <- l+1),
// 0xB1 = quad_perm xor1, 0x4E = quad_perm xor2, 0x128 = row_ror:8 (xor8).
template<int CTRL>
__device__ __forceinline__ float dppf(float x) {
  return __int_as_float(__builtin_amdgcn_mov_dpp(__float_as_int(x), CTRL, 0xF, 0xF, true));
}

// ---------------------------------------------------------------------------
// MFMA 3x3 SAME conv, co-tile split (proven kernel).
// ---------------------------------------------------------------------------
template<int COUT, int TILES, bool SE>
__global__ __launch_bounds__(256) void k_conv(
    const float* __restrict__ inA, const float* __restrict__ inB,
    const float* __restrict__ wA, const float* __restrict__ bA,
    const float* __restrict__ wB, const float* __restrict__ bB,
    float* __restrict__ outA, float* __restrict__ outB,
    int actA, int actB,
    const float* __restrict__ x,
    const float* __restrict__ sw1, const float* __restrict__ sb1,
    const float* __restrict__ sw2, const float* __restrict__ sb2,
    float* __restrict__ seo) {
  __shared__ unsigned short Xl[256 * 64];
  __shared__ unsigned short Wl[9 * 16 * 64];
  __shared__ float sp[64];
  __shared__ float sh1[32];
  const int b = blockIdx.x;
  const int t = threadIdx.x;

  if (SE && b >= 8 * TILES) {
    const int n = b - 8 * TILES;
    const int c = t >> 2, part = t & 3;
    const float* xp = x + (n * 64 + c) * 256 + part * 64;
    float s = 0.f;
    for (int k = 0; k < 64; ++k) s += xp[k];
    s += __shfl_xor(s, 1, 64);
    s += __shfl_xor(s, 2, 64);
    if (part == 0) sp[c] = s * (1.f / 256.f);
    __syncthreads();
    if (t < 32) {
      float a = sb1[t];
      for (int k = 0; k < 64; ++k) a += sw1[t * 64 + k] * sp[k];
      sh1[t] = a > 0.f ? a : 0.01f * a;
    }
    __syncthreads();
    if (t < 16) {
      float a = sb2[t];
      for (int k = 0; k < 32; ++k) a += sw2[t * 32 + k] * sh1[k];
      seo[n * 16 + t] = 1.f / (1.f + __expf(-a));
    }
    return;
  }

  const int n = b & 3;
  const int q = b >> 2;
  const int br = (q >= TILES) ? 1 : 0;
  const int ct = q - br * TILES;
  const int co0 = ct * 16;
  const float* inp = (br ? inB : inA) + n * 64 * 256;
  const float* wsrc = br ? wB : wA;
  const float* bias = br ? bB : bA;
  float* outp = (br ? outB : outA) + n * COUT * 256;
  const int act = br ? actB : actA;

  {
    const int p = t;
    #pragma unroll
    for (int q8 = 0; q8 < 8; ++q8) {
      vs8 v;
      #pragma unroll
      for (int j = 0; j < 8; ++j) v[j] = (short)f2bf(inp[(8 * q8 + j) * 256 + p]);
      *(vs8*)&Xl[p * 64 + ((q8 ^ (p & 7)) << 3)] = v;
    }
  }
  {
    const int col = t >> 4;
    const int sub = t & 15;
    const int co = co0 + col;
    if (co < COUT) {
      const float* wp = wsrc + (co * 64 + sub * 4) * 9;
      #pragma unroll
      for (int cc = 0; cc < 4; ++cc) {
        const int ci = sub * 4 + cc;
        #pragma unroll
        for (int e = 0; e < 9; ++e)
          Wl[(e * 16 + col) * 64 + (ci ^ ((col & 7) << 3))] = f2bf(wp[cc * 9 + e]);
      }
    } else {
      #pragma unroll
      for (int cc = 0; cc < 4; ++cc) {
        const int ci = sub * 4 + cc;
        #pragma unroll
        for (int e = 0; e < 9; ++e)
          Wl[(e * 16 + col) * 64 + (ci ^ ((col & 7) << 3))] = 0;
      }
    }
  }
  __syncthreads();

  const int w = t >> 6, lane = t & 63;
  const int px = lane & 15, kg = lane >> 4;
  vf4 acc[4];
  #pragma unroll
  for (int mt = 0; mt < 4; ++mt) acc[mt] = (vf4)0.f;

  for (int e = 0; e < 9; ++e) {
    const int dy = e / 3 - 1, dx = e % 3 - 1;
    const bool xok = (dx == 0) || (dx < 0 ? (px > 0) : (px < 15));
    const int xoff = xok ? dx : 0;
    #pragma unroll
    for (int ks = 0; ks < 2; ++ks) {
      vs8 bf = *(const vs8*)&Wl[(e * 16 + px) * 64 + (((ks * 4 + kg) ^ (px & 7)) << 3)];
      #pragma unroll
      for (int mt = 0; mt < 4; ++mt) {
        const int yy = 4 * w + mt + dy;
        if (yy < 0 || yy > 15) continue;
        const int ps = yy * 16 + px + xoff;
        vs8 a = *(const vs8*)&Xl[ps * 64 + (((ks * 4 + kg) ^ (ps & 7)) << 3)];
        if (!xok) a = (vs8)(short)0;
        acc[mt] = __builtin_amdgcn_mfma_f32_16x16x32_bf16(a, bf, acc[mt], 0, 0, 0);
      }
    }
  }

  const int co = co0 + px;
  if (co < COUT) {
    const float bv = bias[co];
    #pragma unroll
    for (int mt = 0; mt < 4; ++mt) {
      const int y = 4 * w + mt;
      vf4 v = acc[mt];
      #pragma unroll
      for (int j = 0; j < 4; ++j) {
        float s = v[j] + bv;
        if (act == 1) s = s > 0.f ? s : 0.01f * s;
        else if (act == 2) s = 1.f / (1.f + __expf(-s));
        v[j] = s;
      }
      *(vf4*)&outp[co * 256 + y * 16 + kg * 4] = v;
    }
  }
}

// ---------------------------------------------------------------------------
// Fused GroupNorm(1,16) + SE + post conv (proven kernel).
// ---------------------------------------------------------------------------
__global__ __launch_bounds__(512) void k_post(
    const float* __restrict__ sol, const float* __restrict__ se,
    const float* __restrict__ gn_w, const float* __restrict__ gn_b,
    const float* __restrict__ pw, const float* __restrict__ pb,
    float* __restrict__ out) {
  __shared__ unsigned short Hl[256 * 24];
  __shared__ unsigned short Wp[9 * 128 * 24];
  __shared__ float rs[8];
  __shared__ float rs2[8];
  const int n = blockIdx.x;
  const int t = threadIdx.x;
  const int w = t >> 6, lane = t & 63;

  float v[8];
  {
    const vf4* s4 = (const vf4*)(sol + n * 4096 + 8 * t);
    vf4 a = s4[0], b = s4[1];
    v[0]=a[0];v[1]=a[1];v[2]=a[2];v[3]=a[3];v[4]=b[0];v[5]=b[1];v[6]=b[2];v[7]=b[3];
  }
  float s = 0.f, s2 = 0.f;
  #pragma unroll
  for (int k = 0; k < 8; ++k) { s += v[k]; s2 += v[k] * v[k]; }
  #pragma unroll
  for (int o = 1; o <= 32; o <<= 1) { s += __shfl_xor(s, o, 64); s2 += __shfl_xor(s2, o, 64); }
  if (lane == 0) { rs[w] = s; rs2[w] = s2; }

  {
    const int co = t >> 2, sub = t & 3;
    const float* wp0 = pw + (co * 16 + sub * 4) * 9;
    #pragma unroll
    for (int cc = 0; cc < 4; ++cc) {
      const int ci = sub * 4 + cc;
      #pragma unroll
      for (int e = 0; e < 9; ++e)
        Wp[(e * 128 + co) * 24 + ci] = f2bf(wp0[cc * 9 + e]);
    }
  }
  __syncthreads();
  float sm = 0.f, sq = 0.f;
  #pragma unroll
  for (int k = 0; k < 8; ++k) { sm += rs[k]; sq += rs2[k]; }
  const float mu = sm * (1.f / 4096.f);
  const float rstd = rsqrtf(sq * (1.f / 4096.f) - mu * mu + 1e-5f);

  const int c = t >> 5;
  const int p0 = (8 * t) & 255;
  const float sev = se[n * 16 + c];
  const float sc = rstd * gn_w[c] * sev;
  const float of = (gn_b[c] - mu * rstd * gn_w[c]) * sev;
  #pragma unroll
  for (int k = 0; k < 8; ++k) Hl[(p0 + k) * 24 + c] = f2bf(v[k] * sc + of);
  __syncthreads();

  const int cl = lane & 31, h = lane >> 5;
  const int px = cl & 15, y0 = 2 * w + (cl >> 4);
  vf16 acc[4];
  #pragma unroll
  for (int nt = 0; nt < 4; ++nt) acc[nt] = (vf16)0.f;
  for (int e = 0; e < 9; ++e) {
    const int dy = e / 3 - 1, dx = e % 3 - 1;
    const int yy = y0 + dy, xx = px + dx;
    const bool ok = (yy >= 0 && yy < 16 && xx >= 0 && xx < 16);
    const int ps = ok ? yy * 16 + xx : 0;
    vs8 a = *(const vs8*)&Hl[ps * 24 + h * 8];
    if (!ok) a = (vs8)(short)0;
    #pragma unroll
    for (int nt = 0; nt < 4; ++nt) {
      vs8 bf = *(const vs8*)&Wp[(e * 128 + nt * 32 + cl) * 24 + h * 8];
      acc[nt] = __builtin_amdgcn_mfma_f32_32x32x16_bf16(a, bf, acc[nt], 0, 0, 0);
    }
  }
  float* op = out + n * 32768;
  #pragma unroll
  for (int nt = 0; nt < 4; ++nt) {
    const int co = nt * 32 + cl;
    const float bv = pb[co];
    #pragma unroll
    for (int rq = 0; rq < 4; ++rq) {
      vf4 vv;
      #pragma unroll
      for (int j = 0; j < 4; ++j) vv[j] = acc[nt][rq * 4 + j] + bv;
      *(vf4*)&op[co * 256 + 32 * w + 8 * rq + 4 * h] = vv;
    }
  }
}

// ---------------------------------------------------------------------------
// Wave-local Chebyshev(NCHEB=8)-PCG, DPP SpMV (proven kernel).
// One 64-lane wave per (system, component); 32 blocks, 1 wave/CU.
// Lane l owns pixels (y=l&15, x=4*(l>>4)+k); up/down = DPP wave shifts.
// ---------------------------------------------------------------------------
__global__ __launch_bounds__(64) void k_pcg(
    const float* __restrict__ att, const float* __restrict__ grad,
    float* __restrict__ sol, int maxit, float tol2) {
  const int unit = blockIdx.x;
  const int sys = unit >> 1;
  const int wv = unit & 1;
  const int l = threadIdx.x & 63;
  const int row = l & 15;
  const int c4 = l >> 4;
  const int i0 = 16 * row + 4 * c4;

  const int n = sys >> 2, g = sys & 3;
  const float* ab = att + (n * 40 + g * 10) * 256;
  const float* gb = grad + (n * 40 + g * 10) * 256;

  int era, eda, erb, edb, ec, fa, fb;
  if (wv == 0) { fa = 0; fb = 2; era = 4; eda = 9; erb = 2; edb = 7; ec = 0; }
  else         { fa = 1; fb = 3; era = 8; eda = 5; erb = 6; edb = 3; ec = 1; }

  auto L4 = [](const float* p) { return *reinterpret_cast<const float4*>(p); };
  auto unp = [](float4 v, float* o) { o[0] = v.x; o[1] = v.y; o[2] = v.z; o[3] = v.w; };

  float wLa[4], wRa[4], wUa[4], wDa[4], wXa[4], dga[4], iva[4], rsa[4];
  float wLb[4], wRb[4], wUb[4], wDb[4], wXb[4], dgb[4], ivb[4], rsb[4];

  float rA[4], gA[4], dA[4], hA[4], uA[4] = {0,0,0,0}, vA[4] = {0,0,0,0};
  unp(L4(ab + era * 256 + i0), rA); unp(L4(gb + era * 256 + i0), gA);
  unp(L4(ab + eda * 256 + i0), dA); unp(L4(gb + eda * 256 + i0), hA);
  if (row > 0) { unp(L4(ab + eda * 256 + i0 - 16), uA); unp(L4(gb + eda * 256 + i0 - 16), vA); }
  float rlA = (l > 0) ? ab[era * 256 + i0 - 1] : 0.f;
  float glA = (l > 0) ? gb[era * 256 + i0 - 1] : 0.f;
  float cX[4], gX[4], cU[4] = {0,0,0,0}, gU[4] = {0,0,0,0};
  unp(L4(ab + ec * 256 + i0), cX); unp(L4(gb + ec * 256 + i0), gX);
  float clX = 0.f, glX = 0.f;
  if (wv == 0) { if (l > 0) { clX = ab[ec * 256 + i0 - 1]; glX = gb[ec * 256 + i0 - 1]; } }
  else if (row > 0) { unp(L4(ab + ec * 256 + i0 - 16), cU); unp(L4(gb + ec * 256 + i0 - 16), gU); }

  #pragma unroll
  for (int k = 0; k < 4; ++k) {
    wRa[k] = (k < 3 || c4 < 3) ? rA[k] * rA[k] : 0.f;
    wLa[k] = (k > 0) ? rA[k-1] * rA[k-1] : ((c4 > 0) ? rlA * rlA : 0.f);
    wDa[k] = (row < 15) ? dA[k] * dA[k] : 0.f;
    wUa[k] = (row > 0) ? uA[k] * uA[k] : 0.f;
    float rhs = wRa[k] * gA[k] - wLa[k] * ((k > 0) ? gA[k-1] : glA)
              + wDa[k] * hA[k] - wUa[k] * vA[k];
    float wx, gx;
    if (wv == 0) {
      wx = (k > 0) ? cX[k-1] * cX[k-1] : ((c4 > 0) ? clX * clX : 0.f);
      gx = (k > 0) ? gX[k-1] : glX;
    } else {
      wx = (row > 0) ? cU[k] * cU[k] : 0.f;
      gx = gU[k];
    }
    wXa[k] = wx;
    rhs -= wx * gx;
    rsa[k] = rhs;
    dga[k] = 1e-12f + wRa[k] + wLa[k] + wDa[k] + wUa[k] + wx;
  }

  float rB[4], gB[4], dB[4], hB[4], uB[4] = {0,0,0,0}, vB[4] = {0,0,0,0};
  unp(L4(ab + erb * 256 + i0), rB); unp(L4(gb + erb * 256 + i0), gB);
  unp(L4(ab + edb * 256 + i0), dB); unp(L4(gb + edb * 256 + i0), hB);
  if (row > 0) { unp(L4(ab + edb * 256 + i0 - 16), uB); unp(L4(gb + edb * 256 + i0 - 16), vB); }
  float rlB = (l > 0) ? ab[erb * 256 + i0 - 1] : 0.f;
  float glB = (l > 0) ? gb[erb * 256 + i0 - 1] : 0.f;

  #pragma unroll
  for (int k = 0; k < 4; ++k) {
    wRb[k] = (k < 3 || c4 < 3) ? rB[k] * rB[k] : 0.f;
    wLb[k] = (k > 0) ? rB[k-1] * rB[k-1] : ((c4 > 0) ? rlB * rlB : 0.f);
    wDb[k] = (row < 15) ? dB[k] * dB[k] : 0.f;
    wUb[k] = (row > 0) ? uB[k] * uB[k] : 0.f;
    float wx;
    if (wv == 0) wx = (k < 3 || c4 < 3) ? cX[k] * cX[k] : 0.f;
    else         wx = (row < 15) ? cX[k] * cX[k] : 0.f;
    wXb[k] = wx;
    rsb[k] = wRb[k] * gB[k] - wLb[k] * ((k > 0) ? gB[k-1] : glB)
           + wDb[k] * hB[k] - wUb[k] * vB[k]
           + wx * gX[k];
    dgb[k] = 1e-12f + wRb[k] + wLb[k] + wDb[k] + wUb[k] + wx;
  }

  if (l == 63) {
    float wr = rA[3] * rA[3], wd = dA[3] * dA[3];
    dga[3] += wr + wd;
    rsa[3] += wr * gA[3] + wd * hA[3];
    float wc = cX[3] * cX[3], wrb = rB[3] * rB[3], wdb = dB[3] * dB[3];
    dgb[3] += wc + wrb + wdb;
    rsb[3] += wc * gX[3] + wrb * gB[3] + wdb * hB[3];
  }
  #pragma unroll
  for (int k = 0; k < 4; ++k) { iva[k] = 1.f / dga[k]; ivb[k] = 1.f / dgb[k]; }

  float ua[4], ub[4], wa[4], wb[4];

  auto spmv = [&](const float (&ia_)[4], const float (&ib_)[4],
                  float (&oa)[4], float (&ob)[4]) {
    float aL = __shfl_up(ia_[3], 16, 64);
    float aR = __shfl_down(ia_[0], 16, 64);
    float bL = __shfl_up(ib_[3], 16, 64);
    float bR = __shfl_down(ib_[0], 16, 64);
    float aU[4], aD[4], bU[4], bD[4];
    #pragma unroll
    for (int k = 0; k < 4; ++k) {
      aU[k] = dppf<0x138>(ia_[k]);
      aD[k] = dppf<0x130>(ia_[k]);
      bU[k] = dppf<0x138>(ib_[k]);
      bD[k] = dppf<0x130>(ib_[k]);
    }
    float uaL[4] = {aL, ia_[0], ia_[1], ia_[2]};
    float uaR[4] = {ia_[1], ia_[2], ia_[3], aR};
    float ubL[4] = {bL, ib_[0], ib_[1], ib_[2]};
    float ubR[4] = {ib_[1], ib_[2], ib_[3], bR};
    #pragma unroll
    for (int k = 0; k < 4; ++k) {
      float cA = (wv == 0) ? ubL[k] : bU[k];
      float cB = (wv == 0) ? uaR[k] : aD[k];
      oa[k] = dga[k] * ia_[k] - wLa[k] * uaL[k] - wRa[k] * uaR[k]
            - wUa[k] * aU[k] - wDa[k] * aD[k] - wXa[k] * cA;
      ob[k] = dgb[k] * ib_[k] - wLb[k] * ubL[k] - wRb[k] * ubR[k]
            - wUb[k] * bU[k] - wDb[k] * bD[k] - wXb[k] * cB;
    }
  };

  constexpr float lo = 0.01f, hi = 2.0f;
  constexpr float th = (hi + lo) * 0.5f, dl = (hi - lo) * 0.5f, s1 = th / dl;

  float xa[4] = {0,0,0,0}, xb[4] = {0,0,0,0};
  float ra_[4], rb_[4], pa[4] = {0,0,0,0}, pb_[4] = {0,0,0,0};
  float sa[4] = {0,0,0,0}, sb[4] = {0,0,0,0};
  #pragma unroll
  for (int k = 0; k < 4; ++k) { ra_[k] = rsa[k]; rb_[k] = rsb[k]; }

  auto cheb = [&]() {
    float da_[4], db_[4], ta[4], tb[4], qa[4], qb[4];
    #pragma unroll
    for (int k = 0; k < 4; ++k) {
      da_[k] = (1.0f / th) * iva[k] * ra_[k];
      db_[k] = (1.0f / th) * ivb[k] * rb_[k];
      ua[k] = da_[k]; ub[k] = db_[k];
    }
    spmv(da_, db_, ta, tb);
    #pragma unroll
    for (int k = 0; k < 4; ++k) {
      wa[k] = ta[k]; wb[k] = tb[k];
      qa[k] = ra_[k] - ta[k]; qb[k] = rb_[k] - tb[k];
    }
    float rho = 1.0f / s1;
    #pragma unroll
    for (int j = 1; j < NCHEB; ++j) {
      float rho2 = 1.0f / (2.0f * s1 - rho);
      float c1 = rho2 * rho, c2 = 2.0f * rho2 / dl;
      #pragma unroll
      for (int k = 0; k < 4; ++k) {
        da_[k] = c1 * da_[k] + c2 * iva[k] * qa[k];
        db_[k] = c1 * db_[k] + c2 * ivb[k] * qb[k];
        ua[k] += da_[k]; ub[k] += db_[k];
      }
      spmv(da_, db_, ta, tb);
      #pragma unroll
      for (int k = 0; k < 4; ++k) {
        wa[k] += ta[k]; wb[k] += tb[k];
        qa[k] -= ta[k]; qb[k] -= tb[k];
      }
      rho = rho2;
    }
  };

  float gamma, delta;
  auto dots = [&]() {
    float gp = 0.f, dp = 0.f;
    #pragma unroll
    for (int k = 0; k < 4; ++k) {
      gp += ra_[k] * ua[k] + rb_[k] * ub[k];
      dp += wa[k] * ua[k] + wb[k] * ub[k];
    }
    gp += dppf<0xB1>(gp);            dp += dppf<0xB1>(dp);
    gp += dppf<0x4E>(gp);            dp += dppf<0x4E>(dp);
    gp += __shfl_xor(gp, 4, 64);     dp += __shfl_xor(dp, 4, 64);
    gp += dppf<0x128>(gp);           dp += dppf<0x128>(dp);
    gp += __shfl_xor(gp, 16, 64);    dp += __shfl_xor(dp, 16, 64);
    gp += __shfl_xor(gp, 32, 64);    dp += __shfl_xor(dp, 32, 64);
    gamma = gp; delta = dp;
  };

  cheb();
  dots();
  const float thresh = tol2 * gamma;
  float gamma_old = gamma, alpha_old = 1.f;

  for (int it = 0; it < maxit && gamma > thresh; ++it) {
    float beta = (it == 0) ? 0.f : gamma / gamma_old;
    float alpha = (it == 0) ? gamma / delta
                            : gamma / (delta - beta * gamma / alpha_old);
    #pragma unroll
    for (int k = 0; k < 4; ++k) {
      pa[k] = ua[k] + beta * pa[k];   pb_[k] = ub[k] + beta * pb_[k];
      sa[k] = wa[k] + beta * sa[k];   sb[k] = wb[k] + beta * sb[k];
      xa[k] += alpha * pa[k];         xb[k] += alpha * pb_[k];
      ra_[k] -= alpha * sa[k];        rb_[k] -= alpha * sb[k];
    }
    gamma_old = gamma; alpha_old = alpha;
    cheb();
    dots();
  }

  float4* sol4 = reinterpret_cast<float4*>(sol);
  const int slot = 4 * row + c4;
  sol4[sys * 256 + fa * 64 + slot] = make_float4(xa[0], xa[1], xa[2], xa[3]);
  sol4[sys * 256 + fb * 64 + slot] = make_float4(xb[0], xb[1], xb[2], xb[3]);
}

extern "C" void kernel_launch(void* const* d_in, const int* in_sizes, int n_in,
                              void* d_out, int out_size, void* d_ws, size_t ws_size,
                              hipStream_t stream) {
  const float* x       = (const float*)d_in[0];
  const float* grad_w1 = (const float*)d_in[1];
  const float* grad_b1 = (const float*)d_in[2];
  const float* grad_w2 = (const float*)d_in[3];
  const float* grad_b2 = (const float*)d_in[4];
  const float* att_w1  = (const float*)d_in[5];
  const float* att_b1  = (const float*)d_in[6];
  const float* att_w2  = (const float*)d_in[7];
  const float* att_b2  = (const float*)d_in[8];
  const float* se_w1   = (const float*)d_in[9];
  const float* se_b1   = (const float*)d_in[10];
  const float* se_w2   = (const float*)d_in[11];
  const float* se_b2   = (const float*)d_in[12];
  const float* gn_w    = (const float*)d_in[13];
  const float* gn_b    = (const float*)d_in[14];
  const float* post_w  = (const float*)d_in[15];
  const float* post_b  = (const float*)d_in[16];
  float* out = (float*)d_out;
  float* ws = (float*)d_ws;

  float* t1    = ws;                // 65536 (grad conv1 out)
  float* t2    = ws + 65536;        // 65536 (att conv1 out)
  float* gradb = ws + 131072;       // 40960
  float* attb  = ws + 172032;       // 40960
  float* seb   = ws + 212992;       // 64
  float* solb  = ws;                // 16384 (reuses t1 after conv2)

  // conv1: 2 branches x 4 images x 4 co-tiles = 32 blocks + 4 SE blocks
  k_conv<64, 4, true><<<36, 256, 0, stream>>>(
      x, x, grad_w1, grad_b1, att_w1, att_b1, t1, t2, 1, 1,
      x, se_w1, se_b1, se_w2, se_b2, seb);
  // conv2: 2 x 4 x 3 co-tiles = 24 blocks
  k_conv<40, 3, false><<<24, 256, 0, stream>>>(
      t1, t2, grad_w2, grad_b2, att_w2, att_b2, gradb, attb, 0, 2,
      nullptr, nullptr, nullptr, nullptr, nullptr, nullptr);
  // pcg: 32 blocks x 1 wave (uncontended), DPP SpMV
  k_pcg<<<32, 64, 0, stream>>>(attb, gradb, solb, 100, 3e-6f);
  k_post<<<4, 512, 0, stream>>>(solb, seb, gn_w, gn_b, post_w, post_b, out);
}